// Round 25
// baseline (977.811 us; speedup 1.0000x reference)
//
#include <hip/hip_runtime.h>
#include <hip/hip_bf16.h>
#include <math.h>

#define DIM 384
#define NH 12
#define HD 32
#define NWIN 2048          // B * 64 windows
#define TOKENS 100352      // B * 56 * 56
#define NSTG 6             // W-tile ring depth

typedef unsigned short u16;
typedef unsigned int u32;
typedef __attribute__((ext_vector_type(8))) short bf16x8;
typedef __attribute__((ext_vector_type(4))) float f32x4;

__device__ __forceinline__ float b2f(u16 u){ return __uint_as_float(((u32)u) << 16); }
__device__ __forceinline__ u16 f2b(float f){
  u32 x = __float_as_uint(f);
  return (u16)((x + 0x7FFFu + ((x >> 16) & 1u)) >> 16);   // RNE
}

// async global->LDS, 16B per lane; LDS dest = wave-uniform base + lane*16
__device__ __forceinline__ void gld16(void* lds, const void* g){
  __builtin_amdgcn_global_load_lds((const __attribute__((address_space(1))) u32*)g,
                                   (__attribute__((address_space(3))) u32*)lds, 16, 0, 0);
}

// ---------------- weight pre-convert fp32 -> bf16 ----------------
// w1s/w2s/pws: staging-tile layout. Tile = 8KB = [128 rows][4 granules][8 elems],
// granule pre-swizzled with selector s(r) = (r>>1)&3 (bank-spread verified:
// conflicts 3.05e7 -> 1.56e6). qwbf: plain [row][k] bf16.
__global__ void k_wconv(const float* __restrict__ w1, const float* __restrict__ w2,
                        const float* __restrict__ qw, const float* __restrict__ pw,
                        u16* __restrict__ w1s, u16* __restrict__ w2s,
                        u16* __restrict__ qwbf, u16* __restrict__ pws){
  const int n12 = 1536*384, n3 = 1152*384, n4 = 384*384;
  for (int d = blockIdx.x*blockDim.x + threadIdx.x; d < n12; d += gridDim.x*blockDim.x){
    int tile = d >> 12, w = d & 4095;
    int rowl = w >> 5, g = (w >> 3) & 3, e = w & 7;
    int hci = tile / 12, rem = tile - hci*12;
    int kk = ((g ^ ((rowl >> 1) & 3)) << 3) + e;
    w1s[d] = f2b(w1[(size_t)(hci*128 + rowl)*384 + rem*32 + kk]);
    int ks = rem / 3, t = rem - ks*3;
    w2s[d] = f2b(w2[(size_t)(t*128 + rowl)*1536 + hci*128 + ks*32 + kk]);
    if (d < n3) qwbf[d] = f2b(qw[d]);
    if (d < n4){
      int pt = d >> 12, pwd = d & 4095;
      int prl = pwd >> 5, pg = (pwd >> 3) & 3, pe = pwd & 7;
      int pks = pt / 3, ptt = pt - pks*3;
      int pkk = ((pg ^ ((prl >> 1) & 3)) << 3) + pe;
      pws[d] = f2b(pw[(size_t)(ptt*128 + prl)*384 + pks*32 + pkk]);
    }
  }
}

// ---------------- CPB bias table: tab[169][12] ----------------
__global__ void k_bias(const float* __restrict__ w1, const float* __restrict__ b1,
                       const float* __restrict__ w2, float* __restrict__ tab){
  __shared__ float hid[512];
  int e = blockIdx.x;
  int i = e / 13, j = e % 13;
  float t0 = (float)(i - 6) * (8.0f / 6.0f);
  float t1 = (float)(j - 6) * (8.0f / 6.0f);
  t0 = copysignf(log2f(fabsf(t0) + 1.f) * (1.f / 3.f), t0);
  t1 = copysignf(log2f(fabsf(t1) + 1.f) * (1.f / 3.f), t1);
  for (int jj = threadIdx.x; jj < 512; jj += blockDim.x)
    hid[jj] = fmaxf(w1[jj*2]*t0 + w1[jj*2+1]*t1 + b1[jj], 0.f);
  __syncthreads();
  if (threadIdx.x < 12){
    float s = 0.f;
    for (int jj = 0; jj < 512; ++jj) s += hid[jj] * w2[threadIdx.x*512 + jj];
    tab[e*12 + threadIdx.x] = s;
  }
}

// ---------------- expand: biasfull[h][i*49+j] = 16*sigmoid(tab[rpi(i,j)][h]) ----------------
__global__ void k_bias2(const float* __restrict__ tab, float* __restrict__ biasfull){
  int h = blockIdx.x;
  for (int e = threadIdx.x; e < 49*49; e += blockDim.x){
    int i = e / 49, j = e - (e/49)*49;
    int ih = i/7, iw = i - ih*7, jh = j/7, jw = j - jh*7;
    float bv = tab[((ih-jh+6)*13 + (iw-jw+6))*12 + h];
    biasfull[h*2401 + e] = 16.f / (1.f + expf(-bv));
  }
}

// ---------------- k_qkv: windowed QKV GEMM, LDS double-buffered ----------------
__device__ __forceinline__ void qkv_stage(
    int kc, char* Ad, char* Bd, const float* __restrict__ x, size_t asrc,
    bool arok, int ar, int aq, const u16* __restrict__ bbase, int tid){
  if (arok){
    float4 v4 = *(const float4*)(x + asrc + kc + aq*4);
    u16 p0=f2b(v4.x), p1=f2b(v4.y), p2=f2b(v4.z), p3=f2b(v4.w);
    *(uint2*)(Ad + ar*80 + aq*8) = (uint2){(u32)p0|((u32)p1<<16), (u32)p2|((u32)p3<<16)};
  } else {
    *(uint2*)(Ad + ar*80 + aq*8) = (uint2){0u, 0u};
  }
  #pragma unroll
  for (int i = 0; i < 3; ++i){
    int s = tid + i*512, n = s >> 2, g = s & 3;
    bf16x8 v = *(const bf16x8*)(bbase + (size_t)n*DIM + kc + (g ^ (n&3))*8);
    *(bf16x8*)(Bd + n*64 + g*16) = v;
  }
}

__global__ __launch_bounds__(512, 4) void k_qkv(
    const float* __restrict__ x, const u16* __restrict__ qkvbf,
    const float* __restrict__ q_bias, const float* __restrict__ v_bias,
    const float* __restrict__ logit_scale,
    u16* __restrict__ Qg, u16* __restrict__ Kg, u16* __restrict__ Vg){
  __shared__ __align__(16) char Ab[2][5120];    // [64][80B] bf16
  __shared__ __align__(16) char Bb[2][24576];   // [384][64B] bf16, granule-swz

  int tid = threadIdx.x;
  int lane = tid & 63, wid = tid >> 6;
  int l15 = lane & 15, lg = lane >> 4;
  int wm = wid >> 2, wn = wid & 3;
  int win = blockIdx.x, NT = blockIdx.y;
  int b = win >> 6, wi = win & 63, wh = wi >> 3, ww = wi & 7;

  int ar = tid >> 3, aq = tid & 7;
  bool arok = ar < 49;
  size_t asrc = 0;
  if (arok){
    int th = ar / 7, tw = ar - (ar/7)*7;
    int gh = wh*7 + th + 3; if (gh >= 56) gh -= 56;
    int gw = ww*7 + tw + 3; if (gw >= 56) gw -= 56;
    asrc = ((size_t)(b*3136 + gh*56 + gw))*DIM;
  }
  const u16* bbase = qkvbf + (size_t)NT*384*DIM;

  f32x4 acc[2][6];
  #pragma unroll
  for (int mf = 0; mf < 2; ++mf)
    #pragma unroll
    for (int nf = 0; nf < 6; ++nf) acc[mf][nf] = (f32x4){0.f,0.f,0.f,0.f};

  qkv_stage(0, Ab[0], Bb[0], x, asrc, arok, ar, aq, bbase, tid);
  __syncthreads();

  for (int t = 0; t < 12; ++t){
    int cur = t & 1;
    if (t < 11)
      qkv_stage((t+1)*32, Ab[cur^1], Bb[cur^1], x, asrc, arok, ar, aq, bbase, tid);
    bf16x8 af[2];
    #pragma unroll
    for (int mf = 0; mf < 2; ++mf){
      int row = wm*32 + mf*16 + l15;
      af[mf] = *(const bf16x8*)(Ab[cur] + row*80 + lg*16);
    }
    #pragma unroll
    for (int nf = 0; nf < 6; ++nf){
      int n = wn*96 + nf*16 + l15;
      bf16x8 bfv = *(const bf16x8*)(Bb[cur] + n*64 + ((lg ^ (n&3))*16));
      #pragma unroll
      for (int mf = 0; mf < 2; ++mf)
        acc[mf][nf] = __builtin_amdgcn_mfma_f32_16x16x32_bf16(af[mf], bfv, acc[mf][nf], 0, 0, 0);
    }
    __syncthreads();
  }

  if (NT == 0){        // Q: +bias, cosine norm, * scale
    #pragma unroll
    for (int p = 0; p < 3; ++p){
      int h = wn*3 + p;
      float qb0 = q_bias[h*32 + l15], qb1 = q_bias[h*32 + 16 + l15];
      float sc = __expf(fminf(logit_scale[h], 4.6051702f));
      #pragma unroll
      for (int mf = 0; mf < 2; ++mf)
        #pragma unroll
        for (int r = 0; r < 4; ++r){
          float a0 = acc[mf][2*p][r] + qb0;
          float a1 = acc[mf][2*p+1][r] + qb1;
          float sq = a0*a0 + a1*a1;
          #pragma unroll
          for (int off = 1; off < 16; off <<= 1) sq += __shfl_xor(sq, off, 64);
          float rq = sc / fmaxf(sqrtf(sq), 1e-12f);
          int grow = wm*32 + mf*16 + lg*4 + r;
          if (grow < 49){
            u16* dst = Qg + (size_t)win*18816 + h*1568 + grow*32;
            dst[l15]      = f2b(a0*rq);
            dst[16 + l15] = f2b(a1*rq);
          }
        }
    }
  } else if (NT == 1){ // K: cosine norm only
    #pragma unroll
    for (int p = 0; p < 3; ++p){
      int h = wn*3 + p;
      #pragma unroll
      for (int mf = 0; mf < 2; ++mf)
        #pragma unroll
        for (int r = 0; r < 4; ++r){
          float a0 = acc[mf][2*p][r], a1 = acc[mf][2*p+1][r];
          float sk = a0*a0 + a1*a1;
          #pragma unroll
          for (int off = 1; off < 16; off <<= 1) sk += __shfl_xor(sk, off, 64);
          float rk = 1.f / fmaxf(sqrtf(sk), 1e-12f);
          int grow = wm*32 + mf*16 + lg*4 + r;
          if (grow < 49){
            u16* dst = Kg + (size_t)win*18816 + h*1568 + grow*32;
            dst[l15]      = f2b(a0*rk);
            dst[16 + l15] = f2b(a1*rk);
          }
        }
    }
  } else {             // V: +bias
    #pragma unroll
    for (int nf = 0; nf < 6; ++nf){
      int col = wn*96 + nf*16 + l15;
      int h = col >> 5, c = col & 31;
      float vb = v_bias[col];
      #pragma unroll
      for (int mf = 0; mf < 2; ++mf){
        int gbase = wm*32 + mf*16 + lg*4;
        u16* dst = Vg + (size_t)win*18816 + h*1568 + c;
        #pragma unroll
        for (int r = 0; r < 4; ++r){
          int grow = gbase + r;
          if (grow < 49) dst[grow*32] = f2b(acc[mf][nf][r] + vb);
        }
      }
    }
  }
}

// ---------------- k_attn2: per-window attention (Q/K/V precomputed) ----------------
__global__ __launch_bounds__(256, 3) void k_attn2(
    const u16* __restrict__ Qg, const u16* __restrict__ Kg, const u16* __restrict__ Vg,
    const float* __restrict__ biasfull, u16* __restrict__ outwin){
  __shared__ __align__(16) char pb[4][2304];    // per-wave P [16][144B]

  int tid = threadIdx.x, lane = tid & 63, wid = tid >> 6;
  int l15 = lane & 15, lg = lane >> 4;
  int win = blockIdx.x;
  int wi = win & 63, wh = wi >> 3, ww = wi & 7;

  float mask16[4][4];
  int   bidx[4][4];
  #pragma unroll
  for (int nf = 0; nf < 4; ++nf){
    int j = nf*16 + l15;
    int j2 = j < 49 ? j : 48;
    int jh = j2/7, jw = j2 - jh*7;
    int ghj = wh*7+jh, gwj = ww*7+jw;
    int zj = (ghj<49?0:(ghj<53?1:2))*3 + (gwj<49?0:(gwj<53?1:2));
    #pragma unroll
    for (int r = 0; r < 4; ++r){
      int i = wid*16 + lg*4 + r;
      int i2 = i < 49 ? i : 48;
      int ih = i2/7, iw = i2 - ih*7;
      int ghi = wh*7+ih, gwi = ww*7+iw;
      int zi = (ghi<49?0:(ghi<53?1:2))*3 + (gwi<49?0:(gwi<53?1:2));
      mask16[nf][r] = (j < 49) ? (zi != zj ? -100.f : 0.f) : -1e30f;
      bidx[nf][r]   = i2*49 + j2;
    }
  }

  const u16* qwin = Qg + (size_t)win*18816;
  const u16* kwin = Kg + (size_t)win*18816;
  const u16* vwin = Vg + (size_t)win*18816;
  char* pbw = pb[wid];

  int arow = wid*16 + l15;
  int arc  = arow < 49 ? arow : 48;

  bf16x8 qa[12];
  #pragma unroll
  for (int h = 0; h < 12; ++h)
    qa[h] = *(const bf16x8*)(qwin + h*1568 + arc*32 + lg*8);
  __syncthreads();                              // all Q reads done before outwin writes

  #pragma unroll
  for (int h = 0; h < 12; ++h){
    bf16x8 kb[4];
    #pragma unroll
    for (int nf = 0; nf < 4; ++nf){
      int j = nf*16 + l15; int j2 = j < 49 ? j : 48;
      kb[nf] = *(const bf16x8*)(kwin + h*1568 + j2*32 + lg*8);
    }
    bf16x8 vb0[2], vb1[2];
    #pragma unroll
    for (int ksp = 0; ksp < 2; ++ksp){
      #pragma unroll
      for (int tt = 0; tt < 8; ++tt){
        int j = ksp*32 + lg*8 + tt; int j2 = j < 49 ? j : 48;
        vb0[ksp][tt] = (short)vwin[h*1568 + j2*32 + l15];
        vb1[ksp][tt] = (short)vwin[h*1568 + j2*32 + 16 + l15];
      }
    }
    float bias16[4][4];
    #pragma unroll
    for (int nf = 0; nf < 4; ++nf)
      #pragma unroll
      for (int r = 0; r < 4; ++r)
        bias16[nf][r] = biasfull[h*2401 + bidx[nf][r]];
    f32x4 s[4];
    #pragma unroll
    for (int nf = 0; nf < 4; ++nf)
      s[nf] = __builtin_amdgcn_mfma_f32_16x16x32_bf16(qa[h], kb[nf],
                (f32x4){0.f,0.f,0.f,0.f}, 0, 0, 0);
    #pragma unroll
    for (int nf = 0; nf < 4; ++nf)
      #pragma unroll
      for (int r = 0; r < 4; ++r)
        s[nf][r] += bias16[nf][r] + mask16[nf][r];
    #pragma unroll
    for (int r = 0; r < 4; ++r){
      float m = fmaxf(fmaxf(s[0][r], s[1][r]), fmaxf(s[2][r], s[3][r]));
      #pragma unroll
      for (int off = 1; off < 16; off <<= 1) m = fmaxf(m, __shfl_xor(m, off, 64));
      float e0 = __expf(s[0][r]-m), e1 = __expf(s[1][r]-m);
      float e2 = __expf(s[2][r]-m), e3 = __expf(s[3][r]-m);
      float sum = e0+e1+e2+e3;
      #pragma unroll
      for (int off = 1; off < 16; off <<= 1) sum += __shfl_xor(sum, off, 64);
      float rs = 1.f/sum;
      s[0][r] = e0*rs; s[1][r] = e1*rs; s[2][r] = e2*rs; s[3][r] = e3*rs;
    }
    #pragma unroll
    for (int nf = 0; nf < 4; ++nf){
      int j = nf*16 + l15;
      #pragma unroll
      for (int r = 0; r < 4; ++r)
        *(u16*)(pbw + (lg*4+r)*144 + j*2) = f2b(s[nf][r]);
    }
    f32x4 o0 = (f32x4){0.f,0.f,0.f,0.f}, o1 = o0;
    #pragma unroll
    for (int ksp = 0; ksp < 2; ++ksp){
      bf16x8 pa = *(const bf16x8*)(pbw + l15*144 + ksp*64 + lg*16);
      o0 = __builtin_amdgcn_mfma_f32_16x16x32_bf16(pa, vb0[ksp], o0, 0, 0, 0);
      o1 = __builtin_amdgcn_mfma_f32_16x16x32_bf16(pa, vb1[ksp], o1, 0, 0, 0);
    }
    #pragma unroll
    for (int r = 0; r < 4; ++r){
      int row = wid*16 + lg*4 + r;
      if (row < 49){
        u16* dst = outwin + ((size_t)win*49 + row)*DIM + h*HD;
        dst[l15]      = f2b(o0[r]);
        dst[16 + l15] = f2b(o1[r]);
      }
    }
  }
}

// ---------------- k_proj v3: 32 tokens/block, 2 blocks/CU (k_mlp v9 recipe) ----------------
__global__ __launch_bounds__(512, 4) void k_proj(
    const u16* __restrict__ outwin, const u16* __restrict__ pws,
    const float* __restrict__ proj_b, const float* __restrict__ x,
    const float* __restrict__ n1g, const float* __restrict__ n1b,
    float* __restrict__ x1){
  extern __shared__ char smem[];
  char* sb = smem;                     // [32][768B] bf16, swz ^((r&15)<<4)
  char* Wb = smem + 24576;             // NSTG x 8KB ring (wave-private 1KB slices)

  int tid  = threadIdx.x;
  int lane = tid & 63, wid = tid >> 6;
  int l15  = lane & 15, lg = lane >> 4;
  int gt0 = blockIdx.x * 32;

  for (int e = tid; e < 32*48; e += 512){
    int r = e / 48, q8 = e - (e/48)*48;
    int gtok = gt0 + r;
    int b = gtok / 3136, r2 = gtok - b*3136;
    int oh = r2 / 56, ow = r2 - oh*56;
    int hs = oh + 53; if (hs >= 56) hs -= 56;
    int ws2 = ow + 53; if (ws2 >= 56) ws2 -= 56;
    int win = b*64 + (hs/7)*8 + (ws2/7);
    int row = (hs%7)*7 + (ws2%7);
    bf16x8 v = *(const bf16x8*)(outwin + ((size_t)win*49 + row)*DIM + q8*8);
    *(bf16x8*)(sb + r*768 + ((q8*16) ^ ((r&15)<<4))) = v;
  }

  f32x4 acc[2][3];
  #pragma unroll
  for (int mf = 0; mf < 2; ++mf)
    #pragma unroll
    for (int t = 0; t < 3; ++t){
      float pbv = proj_b[(wid + 8*t)*16 + l15];
      acc[mf][t] = (f32x4){pbv, pbv, pbv, pbv};
    }

  int goff = tid*16;
  int rowl = wid*16 + l15;
  int wswz = (lg ^ ((rowl >> 1) & 3)) << 4;
  #pragma unroll
  for (int sp = 0; sp < NSTG-1; ++sp)
    gld16(Wb + sp*8192 + wid*1024, (const char*)pws + (size_t)sp*8192 + goff);
  __syncthreads();

  #pragma unroll
  for (int ks = 0; ks < 12; ++ks){
    int k0 = ks*32 + lg*8;
    bf16x8 pa[2];
    #pragma unroll
    for (int mf = 0; mf < 2; ++mf){
      int row = mf*16 + l15;
      pa[mf] = *(const bf16x8*)(sb + row*768 + ((k0*2) ^ ((row&15)<<4)));
    }
    #pragma unroll
    for (int t = 0; t < 3; ++t){
      int st = ks*3 + t;
      asm volatile("s_waitcnt vmcnt(4)" ::: "memory");
      __builtin_amdgcn_sched_barrier(0);
      {
        int rp = st + 5;
        char* dst = Wb + ((st+5)%6)*8192 + wid*1024;
        if (rp < 36) gld16(dst, (const char*)pws + (size_t)rp*8192 + goff);
        else         gld16(dst, (const char*)pws + goff);
      }
      char* Wcur = Wb + (st%6)*8192;
      bf16x8 wv = *(const bf16x8*)(Wcur + rowl*64 + wswz);
      #pragma unroll
      for (int mf = 0; mf < 2; ++mf)
        acc[mf][t] = __builtin_amdgcn_mfma_f32_16x16x32_bf16(pa[mf], wv, acc[mf][t], 0, 0, 0);
    }
  }
  __syncthreads();

  float* part = (float*)Wb;            // [32][8][2] f32 (ring dead)
  float* lnf  = (float*)(Wb + 2048);   // [32][2]
  float s1a[2][4], s2a[2][4];
  #pragma unroll
  for (int mf = 0; mf < 2; ++mf)
    #pragma unroll
    for (int r = 0; r < 4; ++r){
      float p1 = acc[mf][0][r] + acc[mf][1][r] + acc[mf][2][r];
      float p2 = acc[mf][0][r]*acc[mf][0][r] + acc[mf][1][r]*acc[mf][1][r]
               + acc[mf][2][r]*acc[mf][2][r];
      #pragma unroll
      for (int off = 1; off < 16; off <<= 1){
        p1 += __shfl_xor(p1, off, 64);
        p2 += __shfl_xor(p2, off, 64);
      }
      s1a[mf][r] = p1; s2a[mf][r] = p2;
    }
  if (l15 == 0){
    #pragma unroll
    for (int mf = 0; mf < 2; ++mf)
      #pragma unroll
      for (int r = 0; r < 4; ++r){
        int row = mf*16 + lg*4 + r;
        part[(row*8 + wid)*2]     = s1a[mf][r];
        part[(row*8 + wid)*2 + 1] = s2a[mf][r];
      }
  }
  __syncthreads();
  if (tid < 32){
    float t1 = 0.f, t2 = 0.f;
    #pragma unroll
    for (int w = 0; w < 8; ++w){
      t1 += part[(tid*8 + w)*2];
      t2 += part[(tid*8 + w)*2 + 1];
    }
    float mu = t1*(1.f/384.f);
    lnf[tid*2]     = mu;
    lnf[tid*2 + 1] = rsqrtf(t2*(1.f/384.f) - mu*mu + 1e-5f);
  }
  __syncthreads();
  #pragma unroll
  for (int mf = 0; mf < 2; ++mf)
    #pragma unroll
    for (int r = 0; r < 4; ++r){
      int row = mf*16 + lg*4 + r;
      float mu = lnf[row*2], rstd = lnf[row*2 + 1];
      #pragma unroll
      for (int t = 0; t < 3; ++t){
        int col = (wid + 8*t)*16 + l15;
        x1[(size_t)(gt0 + row)*DIM + col] =
            (acc[mf][t][r]-mu)*rstd*n1g[col] + n1b[col] + x[(size_t)(gt0 + row)*DIM + col];
      }
    }
}

// ---------------- fused MLP v9c: 32 tokens/block, 2 blocks/CU, tanh-GELU ----------------
__global__ __launch_bounds__(512, 4) void k_mlp(
    const float* __restrict__ x1, const u16* __restrict__ w1s, const float* __restrict__ b1,
    const u16* __restrict__ w2s, const float* __restrict__ b2,
    const float* __restrict__ n2g, const float* __restrict__ n2b,
    float* __restrict__ out){
  extern __shared__ char smem[];
  char* xb = smem;                          // [32][768B] bf16, swz ^((row&15)<<4)
  char* Wb = smem + 24576;                  // NSTG x 8KB ring (wave-private 1KB slices)
  char* hb = smem + 24576 + 49152;          // [32][256B] bf16, swz ^((row&15)<<4)

  int tid  = threadIdx.x;
  int lane = tid & 63, wid = tid >> 6;
  int l15  = lane & 15, lg = lane >> 4;
  int gt0 = blockIdx.x * 32;

  for (int e = tid; e < 32*48; e += 512){
    int r = e / 48, q8 = e - (e/48)*48;
    const float4* src = (const float4*)(x1 + (size_t)(gt0+r)*DIM + q8*8);
    float4 a = src[0], c = src[1];
    bf16x8 v;
    v[0]=(short)f2b(a.x); v[1]=(short)f2b(a.y); v[2]=(short)f2b(a.z); v[3]=(short)f2b(a.w);
    v[4]=(short)f2b(c.x); v[5]=(short)f2b(c.y); v[6]=(short)f2b(c.z); v[7]=(short)f2b(c.w);
    *(bf16x8*)(xb + r*768 + ((q8*16) ^ ((r&15)<<4))) = v;
  }
  int b1c = wid*16 + l15;
  float b1r0 = b1[b1c],          b1r1 = b1[128 + b1c],  b1r2 = b1[256 + b1c];
  float b1r3 = b1[384 + b1c],    b1r4 = b1[512 + b1c],  b1r5 = b1[640 + b1c];
  float b1r6 = b1[768 + b1c],    b1r7 = b1[896 + b1c],  b1r8 = b1[1024 + b1c];
  float b1r9 = b1[1152 + b1c],   b1r10 = b1[1280 + b1c], b1r11 = b1[1408 + b1c];

  f32x4 acc2[2][3];
  #pragma unroll
  for (int mf = 0; mf < 2; ++mf)
    #pragma unroll
    for (int t = 0; t < 3; ++t){
      float bb = b2[(wid + 8*t)*16 + l15];
      acc2[mf][t] = (f32x4){bb, bb, bb, bb};
    }

  int goff = tid*16;
  int rowl = wid*16 + l15;
  int wswz = (lg ^ ((rowl >> 1) & 3)) << 4;
  #pragma unroll
  for (int sp = 0; sp < NSTG-1; ++sp)
    gld16(Wb + sp*8192 + wid*1024, (const char*)w1s + (size_t)sp*8192 + goff);
  __syncthreads();                          // xb visible; prologue stages drained

  for (int hci = 0; hci < 12; ++hci){
    const char* w1c = (const char*)w1s + (size_t)hci*98304;
    const char* w2c = (const char*)w2s + (size_t)hci*98304;
    const char* w1n = (const char*)w1s + (size_t)(hci+1)*98304;

    float bb = hci==0?b1r0 : hci==1?b1r1 : hci==2?b1r2 : hci==3?b1r3 :
               hci==4?b1r4 : hci==5?b1r5 : hci==6?b1r6 : hci==7?b1r7 :
               hci==8?b1r8 : hci==9?b1r9 : hci==10?b1r10 : b1r11;
    f32x4 accH[2];
    #pragma unroll
    for (int mf = 0; mf < 2; ++mf) accH[mf] = (f32x4){bb, bb, bb, bb};

    // ---- GEMM1: 12 barrier-free counted-vmcnt steps ----
    #pragma unroll
    for (int ksp = 0; ksp < 12; ++ksp){
      asm volatile("s_waitcnt vmcnt(4)" ::: "memory");
      __builtin_amdgcn_sched_barrier(0);
      {
        int rp = ksp + 5;
        char* dst = Wb + ((ksp+5)%6)*8192 + wid*1024;
        const char* src = (rp < 12) ? (w1c + (size_t)rp*8192)
                                    : (w2c + (size_t)(rp-12)*8192);
        gld16(dst, src + goff);
      }
      char* Wcur = Wb + (ksp%6)*8192;
      int k0 = ksp*32 + lg*8;
      bf16x8 wfr = *(const bf16x8*)(Wcur + rowl*64 + wswz);
      bf16x8 afr[2];
      #pragma unroll
      for (int mf = 0; mf < 2; ++mf){
        int row = mf*16 + l15;
        afr[mf] = *(const bf16x8*)(xb + row*768 + ((k0*2) ^ ((row&15)<<4)));
      }
      #pragma unroll
      for (int mf = 0; mf < 2; ++mf)
        accH[mf] = __builtin_amdgcn_mfma_f32_16x16x32_bf16(afr[mf], wfr, accH[mf], 0, 0, 0);
    }

    // ---- tanh-form GELU -> hb ----
    #pragma unroll
    for (int mf = 0; mf < 2; ++mf)
      #pragma unroll
      for (int r = 0; r < 4; ++r){
        float v = accH[mf][r];
        float u = v*(1.f + 0.044715f*v*v);
        v = v * __builtin_amdgcn_rcpf(1.f + __expf(-1.5957691f*u));
        int row = mf*16 + lg*4 + r;
        int col = wid*16 + l15;
        *(u16*)(hb + row*256 + ((col*2) ^ ((row&15)<<4))) = f2b(v);
      }
    asm volatile("s_waitcnt lgkmcnt(0)" ::: "memory");
    __builtin_amdgcn_s_barrier();
    __builtin_amdgcn_sched_barrier(0);

    // ---- GEMM2: 12 barrier-free steps (ks 0..3 x t 0..2) ----
    #pragma unroll
    for (int ks = 0; ks < 4; ++ks){
      int k0 = ks*32 + lg*8;
      bf16x8 pa[2];
      #pragma unroll
      for (int mf = 0; mf < 2; ++mf){
        int row = mf*16 + l15;
        pa[mf] = *(const bf16x8*)(hb + row*256 + ((k0*2) ^ ((row&15)<<4)));
      }
      #pragma unroll
      for (int t = 0; t < 3; ++t){
        int st = ks*3 + t;
        asm volatile("s_waitcnt vmcnt(4)" ::: "memory");
        __builtin_amdgcn_sched_barrier(0);
        {
          int rp = st + 17;
          char* dst = Wb + ((st+5)%6)*8192 + wid*1024;
          if (rp < 24)       gld16(dst, w2c + (size_t)(rp-12)*8192 + goff);
          else if (hci < 11) gld16(dst, w1n + (size_t)(rp-24)*8192 + goff);
          else               gld16(dst, (const char*)w1s + goff);   // dummy: rhythm keeper
        }
        char* Wcur = Wb + (st%6)*8192;
        bf16x8 wv = *(const bf16x8*)(Wcur + rowl*64 + wswz);
        #pragma unroll
        for (int mf = 0; mf < 2; ++mf)
          acc2[mf][t] = __builtin_amdgcn_mfma_f32_16x16x32_bf16(pa[mf], wv, acc2[mf][t], 0, 0, 0);
      }
    }
    asm volatile("s_waitcnt lgkmcnt(0)" ::: "memory");
    __builtin_amdgcn_s_barrier();
    __builtin_amdgcn_sched_barrier(0);
  }
  __syncthreads();                          // drain all (incl. dummies) before hb alias

  // ---- LN2 (cross-wave via LDS) + residual epilogue (32 rows) ----
  float* part = (float*)hb;                 // [32][8][2] f32
  float* lnf  = (float*)(hb + 2048);        // [32][2]
  float s1a[2][4], s2a[2][4];
  #pragma unroll
  for (int mf = 0; mf < 2; ++mf)
    #pragma unroll
    for (int r = 0; r < 4; ++r){
      float p1 = acc2[mf][0][r] + acc2[mf][1][r] + acc2[mf][2][r];
      float p2 = acc2[mf][0][r]*acc2[mf][0][r] + acc2[mf][1][r]*acc2[mf][1][r]
               + acc2[mf][2][r]*acc2[mf][2][r];
      #pragma unroll
      for (int off = 1; off < 16; off <<= 1){
        p1 += __shfl_xor(p1, off, 64);
        p2 += __shfl_xor(p2, off, 64);
      }
      s1a[mf][r] = p1; s2a[mf][r] = p2;
    }
  if (l15 == 0){
    #pragma unroll
    for (int mf = 0; mf < 2; ++mf)
      #pragma unroll
      for (int r = 0; r < 4; ++r){
        int row = mf*16 + lg*4 + r;
        part[(row*8 + wid)*2]     = s1a[mf][r];
        part[(row*8 + wid)*2 + 1] = s2a[mf][r];
      }
  }
  __syncthreads();
  if (tid < 32){
    float t1 = 0.f, t2 = 0.f;
    #pragma unroll
    for (int w = 0; w < 8; ++w){
      t1 += part[(tid*8 + w)*2];
      t2 += part[(tid*8 + w)*2 + 1];
    }
    float mu = t1*(1.f/384.f);
    lnf[tid*2]     = mu;
    lnf[tid*2 + 1] = rsqrtf(t2*(1.f/384.f) - mu*mu + 1e-5f);
  }
  __syncthreads();
  #pragma unroll
  for (int mf = 0; mf < 2; ++mf)
    #pragma unroll
    for (int r = 0; r < 4; ++r){
      int row = mf*16 + lg*4 + r;
      float mu = lnf[row*2], rstd = lnf[row*2 + 1];
      #pragma unroll
      for (int t = 0; t < 3; ++t){
        int col = (wid + 8*t)*16 + l15;
        float resid = x1[(size_t)(gt0 + row)*DIM + col];
        out[(size_t)(gt0 + row)*DIM + col] =
            resid + (acc2[mf][t][r]-mu)*rstd*n2g[col] + n2b[col];
      }
    }
}

extern "C" void kernel_launch(void* const* d_in, const int* in_sizes, int n_in,
                              void* d_out, int out_size, void* d_ws, size_t ws_size,
                              hipStream_t stream){
  const float* x           = (const float*)d_in[0];
  const float* qkv_w       = (const float*)d_in[1];
  const float* q_bias      = (const float*)d_in[2];
  const float* v_bias      = (const float*)d_in[3];
  const float* logit_scale = (const float*)d_in[4];
  const float* cpb_w1      = (const float*)d_in[5];
  const float* cpb_b1      = (const float*)d_in[6];
  const float* cpb_w2      = (const float*)d_in[7];
  const float* proj_w      = (const float*)d_in[8];
  const float* proj_b      = (const float*)d_in[9];
  const float* n1g         = (const float*)d_in[10];
  const float* n1b         = (const float*)d_in[11];
  const float* n2g         = (const float*)d_in[12];
  const float* n2b         = (const float*)d_in[13];
  const float* mlp_w1      = (const float*)d_in[14];
  const float* mlp_b1      = (const float*)d_in[15];
  const float* mlp_w2      = (const float*)d_in[16];
  const float* mlp_b2      = (const float*)d_in[17];

  char* ws = (char*)d_ws;
  float* tab      = (float*)ws;
  float* biasfull = (float*)(ws + 8192);
  u16*  Qg     = (u16*)(ws + 126976);                  // aliased by outwin after k_attn2
  u16*  qkvbf  = (u16*)(ws + 126976 + 77070336ull);
  u16*  pws    = (u16*)(ws + 126976 + 77070336ull + 884736ull);
  u16*  w1s    = (u16*)(ws + 126976 + 77070336ull + 884736ull + 294912ull);
  u16*  w2s    = (u16*)(ws + 126976 + 77070336ull + 884736ull + 294912ull + 1179648ull);
  u16*  Kg     = (u16*)d_out;
  u16*  Vg     = Kg + (size_t)NWIN*18816;
  u16*  outwin = Qg;
  float* x1  = (float*)d_out;
  float* out = (float*)d_out;

  hipLaunchKernelGGL(k_bias, dim3(169), dim3(256), 0, stream, cpb_w1, cpb_b1, cpb_w2, tab);
  hipLaunchKernelGGL(k_bias2, dim3(12), dim3(256), 0, stream, tab, biasfull);
  hipLaunchKernelGGL(k_wconv, dim3(1024), dim3(256), 0, stream,
                     mlp_w1, mlp_w2, qkv_w, proj_w, w1s, w2s, qkvbf, pws);
  hipLaunchKernelGGL(k_qkv, dim3(NWIN, 3), dim3(512), 0, stream,
                     x, qkvbf, q_bias, v_bias, logit_scale, Qg, Kg, Vg);
  hipLaunchKernelGGL(k_attn2, dim3(NWIN), dim3(256), 0, stream,
                     Qg, Kg, Vg, biasfull, outwin);
  // dynamic LDS: 24K sb + 48K ring = 73728 B -> 2 blocks/CU
  hipLaunchKernelGGL(k_proj, dim3(TOKENS/32), dim3(512), 73728, stream,
                     outwin, pws, proj_b, x, n1g, n1b, x1);
  // dynamic LDS: 24K xb + 48K ring + 8K hb = 81920 B -> 2 blocks/CU
  hipLaunchKernelGGL(k_mlp, dim3(TOKENS/32), dim3(512), 81920, stream,
                     x1, w1s, mlp_b1, w2s, mlp_b2, n2g, n2b, out);
}

// Round 26
// 976.465 us; speedup vs baseline: 1.0014x; 1.0014x over previous
//
#include <hip/hip_runtime.h>
#include <hip/hip_bf16.h>
#include <math.h>

#define DIM 384
#define NH 12
#define HD 32
#define NWIN 2048          // B * 64 windows
#define TOKENS 100352      // B * 56 * 56
#define NSTG 6             // W-tile ring depth

typedef unsigned short u16;
typedef unsigned int u32;
typedef __attribute__((ext_vector_type(8))) short bf16x8;
typedef __attribute__((ext_vector_type(4))) float f32x4;

__device__ __forceinline__ float b2f(u16 u){ return __uint_as_float(((u32)u) << 16); }
__device__ __forceinline__ u16 f2b(float f){
  u32 x = __float_as_uint(f);
  return (u16)((x + 0x7FFFu + ((x >> 16) & 1u)) >> 16);   // RNE
}

// async global->LDS, 16B per lane; LDS dest = wave-uniform base + lane*16
__device__ __forceinline__ void gld16(void* lds, const void* g){
  __builtin_amdgcn_global_load_lds((const __attribute__((address_space(1))) u32*)g,
                                   (__attribute__((address_space(3))) u32*)lds, 16, 0, 0);
}

// ---------------- weight pre-convert fp32 -> bf16 ----------------
// w1s/w2s/pws: staging-tile layout. Tile = 8KB = [128 rows][4 granules][8 elems],
// granule pre-swizzled with selector s(r) = (r>>1)&3 (bank-spread verified:
// conflicts 3.05e7 -> 1.56e6). qwbf: plain [row][k] bf16.
__global__ void k_wconv(const float* __restrict__ w1, const float* __restrict__ w2,
                        const float* __restrict__ qw, const float* __restrict__ pw,
                        u16* __restrict__ w1s, u16* __restrict__ w2s,
                        u16* __restrict__ qwbf, u16* __restrict__ pws){
  const int n12 = 1536*384, n3 = 1152*384, n4 = 384*384;
  for (int d = blockIdx.x*blockDim.x + threadIdx.x; d < n12; d += gridDim.x*blockDim.x){
    int tile = d >> 12, w = d & 4095;
    int rowl = w >> 5, g = (w >> 3) & 3, e = w & 7;
    int hci = tile / 12, rem = tile - hci*12;
    int kk = ((g ^ ((rowl >> 1) & 3)) << 3) + e;
    w1s[d] = f2b(w1[(size_t)(hci*128 + rowl)*384 + rem*32 + kk]);
    int ks = rem / 3, t = rem - ks*3;
    w2s[d] = f2b(w2[(size_t)(t*128 + rowl)*1536 + hci*128 + ks*32 + kk]);
    if (d < n3) qwbf[d] = f2b(qw[d]);
    if (d < n4){
      int pt = d >> 12, pwd = d & 4095;
      int prl = pwd >> 5, pg = (pwd >> 3) & 3, pe = pwd & 7;
      int pks = pt / 3, ptt = pt - pks*3;
      int pkk = ((pg ^ ((prl >> 1) & 3)) << 3) + pe;
      pws[d] = f2b(pw[(size_t)(ptt*128 + prl)*384 + pks*32 + pkk]);
    }
  }
}

// ---------------- CPB bias table: tab[169][12] ----------------
__global__ void k_bias(const float* __restrict__ w1, const float* __restrict__ b1,
                       const float* __restrict__ w2, float* __restrict__ tab){
  __shared__ float hid[512];
  int e = blockIdx.x;
  int i = e / 13, j = e % 13;
  float t0 = (float)(i - 6) * (8.0f / 6.0f);
  float t1 = (float)(j - 6) * (8.0f / 6.0f);
  t0 = copysignf(log2f(fabsf(t0) + 1.f) * (1.f / 3.f), t0);
  t1 = copysignf(log2f(fabsf(t1) + 1.f) * (1.f / 3.f), t1);
  for (int jj = threadIdx.x; jj < 512; jj += blockDim.x)
    hid[jj] = fmaxf(w1[jj*2]*t0 + w1[jj*2+1]*t1 + b1[jj], 0.f);
  __syncthreads();
  if (threadIdx.x < 12){
    float s = 0.f;
    for (int jj = 0; jj < 512; ++jj) s += hid[jj] * w2[threadIdx.x*512 + jj];
    tab[e*12 + threadIdx.x] = s;
  }
}

// ---------------- expand: biasfull[h][i*49+j] = 16*sigmoid(tab[rpi(i,j)][h]) ----------------
__global__ void k_bias2(const float* __restrict__ tab, float* __restrict__ biasfull){
  int h = blockIdx.x;
  for (int e = threadIdx.x; e < 49*49; e += blockDim.x){
    int i = e / 49, j = e - (e/49)*49;
    int ih = i/7, iw = i - ih*7, jh = j/7, jw = j - jh*7;
    float bv = tab[((ih-jh+6)*13 + (iw-jw+6))*12 + h];
    biasfull[h*2401 + e] = 16.f / (1.f + expf(-bv));
  }
}

// ---------------- k_qkv: windowed QKV GEMM, LDS double-buffered ----------------
__device__ __forceinline__ void qkv_stage(
    int kc, char* Ad, char* Bd, const float* __restrict__ x, size_t asrc,
    bool arok, int ar, int aq, const u16* __restrict__ bbase, int tid){
  if (arok){
    float4 v4 = *(const float4*)(x + asrc + kc + aq*4);
    u16 p0=f2b(v4.x), p1=f2b(v4.y), p2=f2b(v4.z), p3=f2b(v4.w);
    *(uint2*)(Ad + ar*80 + aq*8) = (uint2){(u32)p0|((u32)p1<<16), (u32)p2|((u32)p3<<16)};
  } else {
    *(uint2*)(Ad + ar*80 + aq*8) = (uint2){0u, 0u};
  }
  #pragma unroll
  for (int i = 0; i < 3; ++i){
    int s = tid + i*512, n = s >> 2, g = s & 3;
    bf16x8 v = *(const bf16x8*)(bbase + (size_t)n*DIM + kc + (g ^ (n&3))*8);
    *(bf16x8*)(Bd + n*64 + g*16) = v;
  }
}

__global__ __launch_bounds__(512, 4) void k_qkv(
    const float* __restrict__ x, const u16* __restrict__ qkvbf,
    const float* __restrict__ q_bias, const float* __restrict__ v_bias,
    const float* __restrict__ logit_scale,
    u16* __restrict__ Qg, u16* __restrict__ Kg, u16* __restrict__ Vg){
  __shared__ __align__(16) char Ab[2][5120];    // [64][80B] bf16
  __shared__ __align__(16) char Bb[2][24576];   // [384][64B] bf16, granule-swz

  int tid = threadIdx.x;
  int lane = tid & 63, wid = tid >> 6;
  int l15 = lane & 15, lg = lane >> 4;
  int wm = wid >> 2, wn = wid & 3;
  int win = blockIdx.x, NT = blockIdx.y;
  int b = win >> 6, wi = win & 63, wh = wi >> 3, ww = wi & 7;

  int ar = tid >> 3, aq = tid & 7;
  bool arok = ar < 49;
  size_t asrc = 0;
  if (arok){
    int th = ar / 7, tw = ar - (ar/7)*7;
    int gh = wh*7 + th + 3; if (gh >= 56) gh -= 56;
    int gw = ww*7 + tw + 3; if (gw >= 56) gw -= 56;
    asrc = ((size_t)(b*3136 + gh*56 + gw))*DIM;
  }
  const u16* bbase = qkvbf + (size_t)NT*384*DIM;

  f32x4 acc[2][6];
  #pragma unroll
  for (int mf = 0; mf < 2; ++mf)
    #pragma unroll
    for (int nf = 0; nf < 6; ++nf) acc[mf][nf] = (f32x4){0.f,0.f,0.f,0.f};

  qkv_stage(0, Ab[0], Bb[0], x, asrc, arok, ar, aq, bbase, tid);
  __syncthreads();

  for (int t = 0; t < 12; ++t){
    int cur = t & 1;
    if (t < 11)
      qkv_stage((t+1)*32, Ab[cur^1], Bb[cur^1], x, asrc, arok, ar, aq, bbase, tid);
    bf16x8 af[2];
    #pragma unroll
    for (int mf = 0; mf < 2; ++mf){
      int row = wm*32 + mf*16 + l15;
      af[mf] = *(const bf16x8*)(Ab[cur] + row*80 + lg*16);
    }
    #pragma unroll
    for (int nf = 0; nf < 6; ++nf){
      int n = wn*96 + nf*16 + l15;
      bf16x8 bfv = *(const bf16x8*)(Bb[cur] + n*64 + ((lg ^ (n&3))*16));
      #pragma unroll
      for (int mf = 0; mf < 2; ++mf)
        acc[mf][nf] = __builtin_amdgcn_mfma_f32_16x16x32_bf16(af[mf], bfv, acc[mf][nf], 0, 0, 0);
    }
    __syncthreads();
  }

  if (NT == 0){        // Q: +bias, cosine norm, * scale
    #pragma unroll
    for (int p = 0; p < 3; ++p){
      int h = wn*3 + p;
      float qb0 = q_bias[h*32 + l15], qb1 = q_bias[h*32 + 16 + l15];
      float sc = __expf(fminf(logit_scale[h], 4.6051702f));
      #pragma unroll
      for (int mf = 0; mf < 2; ++mf)
        #pragma unroll
        for (int r = 0; r < 4; ++r){
          float a0 = acc[mf][2*p][r] + qb0;
          float a1 = acc[mf][2*p+1][r] + qb1;
          float sq = a0*a0 + a1*a1;
          #pragma unroll
          for (int off = 1; off < 16; off <<= 1) sq += __shfl_xor(sq, off, 64);
          float rq = sc / fmaxf(sqrtf(sq), 1e-12f);
          int grow = wm*32 + mf*16 + lg*4 + r;
          if (grow < 49){
            u16* dst = Qg + (size_t)win*18816 + h*1568 + grow*32;
            dst[l15]      = f2b(a0*rq);
            dst[16 + l15] = f2b(a1*rq);
          }
        }
    }
  } else if (NT == 1){ // K: cosine norm only
    #pragma unroll
    for (int p = 0; p < 3; ++p){
      int h = wn*3 + p;
      #pragma unroll
      for (int mf = 0; mf < 2; ++mf)
        #pragma unroll
        for (int r = 0; r < 4; ++r){
          float a0 = acc[mf][2*p][r], a1 = acc[mf][2*p+1][r];
          float sk = a0*a0 + a1*a1;
          #pragma unroll
          for (int off = 1; off < 16; off <<= 1) sk += __shfl_xor(sk, off, 64);
          float rk = 1.f / fmaxf(sqrtf(sk), 1e-12f);
          int grow = wm*32 + mf*16 + lg*4 + r;
          if (grow < 49){
            u16* dst = Kg + (size_t)win*18816 + h*1568 + grow*32;
            dst[l15]      = f2b(a0*rk);
            dst[16 + l15] = f2b(a1*rk);
          }
        }
    }
  } else {             // V: +bias
    #pragma unroll
    for (int nf = 0; nf < 6; ++nf){
      int col = wn*96 + nf*16 + l15;
      int h = col >> 5, c = col & 31;
      float vb = v_bias[col];
      #pragma unroll
      for (int mf = 0; mf < 2; ++mf){
        int gbase = wm*32 + mf*16 + lg*4;
        u16* dst = Vg + (size_t)win*18816 + h*1568 + c;
        #pragma unroll
        for (int r = 0; r < 4; ++r){
          int grow = gbase + r;
          if (grow < 49) dst[grow*32] = f2b(acc[mf][nf][r] + vb);
        }
      }
    }
  }
}

// ---------------- k_attn2: per-window attention (Q/K/V precomputed) ----------------
__global__ __launch_bounds__(256, 3) void k_attn2(
    const u16* __restrict__ Qg, const u16* __restrict__ Kg, const u16* __restrict__ Vg,
    const float* __restrict__ biasfull, u16* __restrict__ outwin){
  __shared__ __align__(16) char pb[4][2304];    // per-wave P [16][144B]

  int tid = threadIdx.x, lane = tid & 63, wid = tid >> 6;
  int l15 = lane & 15, lg = lane >> 4;
  int win = blockIdx.x;
  int wi = win & 63, wh = wi >> 3, ww = wi & 7;

  float mask16[4][4];
  int   bidx[4][4];
  #pragma unroll
  for (int nf = 0; nf < 4; ++nf){
    int j = nf*16 + l15;
    int j2 = j < 49 ? j : 48;
    int jh = j2/7, jw = j2 - jh*7;
    int ghj = wh*7+jh, gwj = ww*7+jw;
    int zj = (ghj<49?0:(ghj<53?1:2))*3 + (gwj<49?0:(gwj<53?1:2));
    #pragma unroll
    for (int r = 0; r < 4; ++r){
      int i = wid*16 + lg*4 + r;
      int i2 = i < 49 ? i : 48;
      int ih = i2/7, iw = i2 - ih*7;
      int ghi = wh*7+ih, gwi = ww*7+iw;
      int zi = (ghi<49?0:(ghi<53?1:2))*3 + (gwi<49?0:(gwi<53?1:2));
      mask16[nf][r] = (j < 49) ? (zi != zj ? -100.f : 0.f) : -1e30f;
      bidx[nf][r]   = i2*49 + j2;
    }
  }

  const u16* qwin = Qg + (size_t)win*18816;
  const u16* kwin = Kg + (size_t)win*18816;
  const u16* vwin = Vg + (size_t)win*18816;
  char* pbw = pb[wid];

  int arow = wid*16 + l15;
  int arc  = arow < 49 ? arow : 48;

  bf16x8 qa[12];
  #pragma unroll
  for (int h = 0; h < 12; ++h)
    qa[h] = *(const bf16x8*)(qwin + h*1568 + arc*32 + lg*8);
  __syncthreads();                              // all Q reads done before outwin writes

  #pragma unroll
  for (int h = 0; h < 12; ++h){
    bf16x8 kb[4];
    #pragma unroll
    for (int nf = 0; nf < 4; ++nf){
      int j = nf*16 + l15; int j2 = j < 49 ? j : 48;
      kb[nf] = *(const bf16x8*)(kwin + h*1568 + j2*32 + lg*8);
    }
    bf16x8 vb0[2], vb1[2];
    #pragma unroll
    for (int ksp = 0; ksp < 2; ++ksp){
      #pragma unroll
      for (int tt = 0; tt < 8; ++tt){
        int j = ksp*32 + lg*8 + tt; int j2 = j < 49 ? j : 48;
        vb0[ksp][tt] = (short)vwin[h*1568 + j2*32 + l15];
        vb1[ksp][tt] = (short)vwin[h*1568 + j2*32 + 16 + l15];
      }
    }
    float bias16[4][4];
    #pragma unroll
    for (int nf = 0; nf < 4; ++nf)
      #pragma unroll
      for (int r = 0; r < 4; ++r)
        bias16[nf][r] = biasfull[h*2401 + bidx[nf][r]];
    f32x4 s[4];
    #pragma unroll
    for (int nf = 0; nf < 4; ++nf)
      s[nf] = __builtin_amdgcn_mfma_f32_16x16x32_bf16(qa[h], kb[nf],
                (f32x4){0.f,0.f,0.f,0.f}, 0, 0, 0);
    #pragma unroll
    for (int nf = 0; nf < 4; ++nf)
      #pragma unroll
      for (int r = 0; r < 4; ++r)
        s[nf][r] += bias16[nf][r] + mask16[nf][r];
    #pragma unroll
    for (int r = 0; r < 4; ++r){
      float m = fmaxf(fmaxf(s[0][r], s[1][r]), fmaxf(s[2][r], s[3][r]));
      #pragma unroll
      for (int off = 1; off < 16; off <<= 1) m = fmaxf(m, __shfl_xor(m, off, 64));
      float e0 = __expf(s[0][r]-m), e1 = __expf(s[1][r]-m);
      float e2 = __expf(s[2][r]-m), e3 = __expf(s[3][r]-m);
      float sum = e0+e1+e2+e3;
      #pragma unroll
      for (int off = 1; off < 16; off <<= 1) sum += __shfl_xor(sum, off, 64);
      float rs = 1.f/sum;
      s[0][r] = e0*rs; s[1][r] = e1*rs; s[2][r] = e2*rs; s[3][r] = e3*rs;
    }
    #pragma unroll
    for (int nf = 0; nf < 4; ++nf){
      int j = nf*16 + l15;
      #pragma unroll
      for (int r = 0; r < 4; ++r)
        *(u16*)(pbw + (lg*4+r)*144 + j*2) = f2b(s[nf][r]);
    }
    f32x4 o0 = (f32x4){0.f,0.f,0.f,0.f}, o1 = o0;
    #pragma unroll
    for (int ksp = 0; ksp < 2; ++ksp){
      bf16x8 pa = *(const bf16x8*)(pbw + l15*144 + ksp*64 + lg*16);
      o0 = __builtin_amdgcn_mfma_f32_16x16x32_bf16(pa, vb0[ksp], o0, 0, 0, 0);
      o1 = __builtin_amdgcn_mfma_f32_16x16x32_bf16(pa, vb1[ksp], o1, 0, 0, 0);
    }
    #pragma unroll
    for (int r = 0; r < 4; ++r){
      int row = wid*16 + lg*4 + r;
      if (row < 49){
        u16* dst = outwin + ((size_t)win*49 + row)*DIM + h*HD;
        dst[l15]      = f2b(o0[r]);
        dst[16 + l15] = f2b(o1[r]);
      }
    }
  }
}

// ---------------- k_proj v3: 32 tokens/block, 2 blocks/CU (k_mlp v9 recipe) ----------------
__global__ __launch_bounds__(512, 4) void k_proj(
    const u16* __restrict__ outwin, const u16* __restrict__ pws,
    const float* __restrict__ proj_b, const float* __restrict__ x,
    const float* __restrict__ n1g, const float* __restrict__ n1b,
    float* __restrict__ x1){
  extern __shared__ char smem[];
  char* sb = smem;                     // [32][768B] bf16, swz ^((r&15)<<4)
  char* Wb = smem + 24576;             // NSTG x 8KB ring (wave-private 1KB slices)

  int tid  = threadIdx.x;
  int lane = tid & 63, wid = tid >> 6;
  int l15  = lane & 15, lg = lane >> 4;
  int gt0 = blockIdx.x * 32;

  for (int e = tid; e < 32*48; e += 512){
    int r = e / 48, q8 = e - (e/48)*48;
    int gtok = gt0 + r;
    int b = gtok / 3136, r2 = gtok - b*3136;
    int oh = r2 / 56, ow = r2 - oh*56;
    int hs = oh + 53; if (hs >= 56) hs -= 56;
    int ws2 = ow + 53; if (ws2 >= 56) ws2 -= 56;
    int win = b*64 + (hs/7)*8 + (ws2/7);
    int row = (hs%7)*7 + (ws2%7);
    bf16x8 v = *(const bf16x8*)(outwin + ((size_t)win*49 + row)*DIM + q8*8);
    *(bf16x8*)(sb + r*768 + ((q8*16) ^ ((r&15)<<4))) = v;
  }

  f32x4 acc[2][3];
  #pragma unroll
  for (int mf = 0; mf < 2; ++mf)
    #pragma unroll
    for (int t = 0; t < 3; ++t){
      float pbv = proj_b[(wid + 8*t)*16 + l15];
      acc[mf][t] = (f32x4){pbv, pbv, pbv, pbv};
    }

  int goff = tid*16;
  int rowl = wid*16 + l15;
  int wswz = (lg ^ ((rowl >> 1) & 3)) << 4;
  #pragma unroll
  for (int sp = 0; sp < NSTG-1; ++sp)
    gld16(Wb + sp*8192 + wid*1024, (const char*)pws + (size_t)sp*8192 + goff);
  __syncthreads();

  #pragma unroll
  for (int ks = 0; ks < 12; ++ks){
    int k0 = ks*32 + lg*8;
    bf16x8 pa[2];
    #pragma unroll
    for (int mf = 0; mf < 2; ++mf){
      int row = mf*16 + l15;
      pa[mf] = *(const bf16x8*)(sb + row*768 + ((k0*2) ^ ((row&15)<<4)));
    }
    #pragma unroll
    for (int t = 0; t < 3; ++t){
      int st = ks*3 + t;
      asm volatile("s_waitcnt vmcnt(4)" ::: "memory");
      __builtin_amdgcn_sched_barrier(0);
      {
        int rp = st + 5;
        char* dst = Wb + ((st+5)%6)*8192 + wid*1024;
        if (rp < 36) gld16(dst, (const char*)pws + (size_t)rp*8192 + goff);
        else         gld16(dst, (const char*)pws + goff);
      }
      char* Wcur = Wb + (st%6)*8192;
      bf16x8 wv = *(const bf16x8*)(Wcur + rowl*64 + wswz);
      #pragma unroll
      for (int mf = 0; mf < 2; ++mf)
        acc[mf][t] = __builtin_amdgcn_mfma_f32_16x16x32_bf16(pa[mf], wv, acc[mf][t], 0, 0, 0);
    }
  }
  __syncthreads();

  float* part = (float*)Wb;            // [32][8][2] f32 (ring dead)
  float* lnf  = (float*)(Wb + 2048);   // [32][2]
  float s1a[2][4], s2a[2][4];
  #pragma unroll
  for (int mf = 0; mf < 2; ++mf)
    #pragma unroll
    for (int r = 0; r < 4; ++r){
      float p1 = acc[mf][0][r] + acc[mf][1][r] + acc[mf][2][r];
      float p2 = acc[mf][0][r]*acc[mf][0][r] + acc[mf][1][r]*acc[mf][1][r]
               + acc[mf][2][r]*acc[mf][2][r];
      #pragma unroll
      for (int off = 1; off < 16; off <<= 1){
        p1 += __shfl_xor(p1, off, 64);
        p2 += __shfl_xor(p2, off, 64);
      }
      s1a[mf][r] = p1; s2a[mf][r] = p2;
    }
  if (l15 == 0){
    #pragma unroll
    for (int mf = 0; mf < 2; ++mf)
      #pragma unroll
      for (int r = 0; r < 4; ++r){
        int row = mf*16 + lg*4 + r;
        part[(row*8 + wid)*2]     = s1a[mf][r];
        part[(row*8 + wid)*2 + 1] = s2a[mf][r];
      }
  }
  __syncthreads();
  if (tid < 32){
    float t1 = 0.f, t2 = 0.f;
    #pragma unroll
    for (int w = 0; w < 8; ++w){
      t1 += part[(tid*8 + w)*2];
      t2 += part[(tid*8 + w)*2 + 1];
    }
    float mu = t1*(1.f/384.f);
    lnf[tid*2]     = mu;
    lnf[tid*2 + 1] = rsqrtf(t2*(1.f/384.f) - mu*mu + 1e-5f);
  }
  __syncthreads();
  #pragma unroll
  for (int mf = 0; mf < 2; ++mf)
    #pragma unroll
    for (int r = 0; r < 4; ++r){
      int row = mf*16 + lg*4 + r;
      float mu = lnf[row*2], rstd = lnf[row*2 + 1];
      #pragma unroll
      for (int t = 0; t < 3; ++t){
        int col = (wid + 8*t)*16 + l15;
        x1[(size_t)(gt0 + row)*DIM + col] =
            (acc[mf][t][r]-mu)*rstd*n1g[col] + n1b[col] + x[(size_t)(gt0 + row)*DIM + col];
      }
    }
}

// ---------------- fused MLP v9c: 32 tokens/block, 2 blocks/CU, tanh-GELU ----------------
__global__ __launch_bounds__(512, 4) void k_mlp(
    const float* __restrict__ x1, const u16* __restrict__ w1s, const float* __restrict__ b1,
    const u16* __restrict__ w2s, const float* __restrict__ b2,
    const float* __restrict__ n2g, const float* __restrict__ n2b,
    float* __restrict__ out){
  extern __shared__ char smem[];
  char* xb = smem;                          // [32][768B] bf16, swz ^((row&15)<<4)
  char* Wb = smem + 24576;                  // NSTG x 8KB ring (wave-private 1KB slices)
  char* hb = smem + 24576 + 49152;          // [32][256B] bf16, swz ^((row&15)<<4)

  int tid  = threadIdx.x;
  int lane = tid & 63, wid = tid >> 6;
  int l15  = lane & 15, lg = lane >> 4;
  int gt0 = blockIdx.x * 32;

  for (int e = tid; e < 32*48; e += 512){
    int r = e / 48, q8 = e - (e/48)*48;
    const float4* src = (const float4*)(x1 + (size_t)(gt0+r)*DIM + q8*8);
    float4 a = src[0], c = src[1];
    bf16x8 v;
    v[0]=(short)f2b(a.x); v[1]=(short)f2b(a.y); v[2]=(short)f2b(a.z); v[3]=(short)f2b(a.w);
    v[4]=(short)f2b(c.x); v[5]=(short)f2b(c.y); v[6]=(short)f2b(c.z); v[7]=(short)f2b(c.w);
    *(bf16x8*)(xb + r*768 + ((q8*16) ^ ((r&15)<<4))) = v;
  }
  int b1c = wid*16 + l15;
  float b1r0 = b1[b1c],          b1r1 = b1[128 + b1c],  b1r2 = b1[256 + b1c];
  float b1r3 = b1[384 + b1c],    b1r4 = b1[512 + b1c],  b1r5 = b1[640 + b1c];
  float b1r6 = b1[768 + b1c],    b1r7 = b1[896 + b1c],  b1r8 = b1[1024 + b1c];
  float b1r9 = b1[1152 + b1c],   b1r10 = b1[1280 + b1c], b1r11 = b1[1408 + b1c];

  f32x4 acc2[2][3];
  #pragma unroll
  for (int mf = 0; mf < 2; ++mf)
    #pragma unroll
    for (int t = 0; t < 3; ++t){
      float bb = b2[(wid + 8*t)*16 + l15];
      acc2[mf][t] = (f32x4){bb, bb, bb, bb};
    }

  int goff = tid*16;
  int rowl = wid*16 + l15;
  int wswz = (lg ^ ((rowl >> 1) & 3)) << 4;
  #pragma unroll
  for (int sp = 0; sp < NSTG-1; ++sp)
    gld16(Wb + sp*8192 + wid*1024, (const char*)w1s + (size_t)sp*8192 + goff);
  __syncthreads();                          // xb visible; prologue stages drained

  for (int hci = 0; hci < 12; ++hci){
    const char* w1c = (const char*)w1s + (size_t)hci*98304;
    const char* w2c = (const char*)w2s + (size_t)hci*98304;
    const char* w1n = (const char*)w1s + (size_t)(hci+1)*98304;

    float bb = hci==0?b1r0 : hci==1?b1r1 : hci==2?b1r2 : hci==3?b1r3 :
               hci==4?b1r4 : hci==5?b1r5 : hci==6?b1r6 : hci==7?b1r7 :
               hci==8?b1r8 : hci==9?b1r9 : hci==10?b1r10 : b1r11;
    f32x4 accH[2];
    #pragma unroll
    for (int mf = 0; mf < 2; ++mf) accH[mf] = (f32x4){bb, bb, bb, bb};

    // ---- GEMM1: 12 barrier-free counted-vmcnt steps ----
    #pragma unroll
    for (int ksp = 0; ksp < 12; ++ksp){
      asm volatile("s_waitcnt vmcnt(4)" ::: "memory");
      __builtin_amdgcn_sched_barrier(0);
      {
        int rp = ksp + 5;
        char* dst = Wb + ((ksp+5)%6)*8192 + wid*1024;
        const char* src = (rp < 12) ? (w1c + (size_t)rp*8192)
                                    : (w2c + (size_t)(rp-12)*8192);
        gld16(dst, src + goff);
      }
      char* Wcur = Wb + (ksp%6)*8192;
      int k0 = ksp*32 + lg*8;
      bf16x8 wfr = *(const bf16x8*)(Wcur + rowl*64 + wswz);
      bf16x8 afr[2];
      #pragma unroll
      for (int mf = 0; mf < 2; ++mf){
        int row = mf*16 + l15;
        afr[mf] = *(const bf16x8*)(xb + row*768 + ((k0*2) ^ ((row&15)<<4)));
      }
      #pragma unroll
      for (int mf = 0; mf < 2; ++mf)
        accH[mf] = __builtin_amdgcn_mfma_f32_16x16x32_bf16(afr[mf], wfr, accH[mf], 0, 0, 0);
    }

    // ---- tanh-form GELU -> hb ----
    #pragma unroll
    for (int mf = 0; mf < 2; ++mf)
      #pragma unroll
      for (int r = 0; r < 4; ++r){
        float v = accH[mf][r];
        float u = v*(1.f + 0.044715f*v*v);
        v = v * __builtin_amdgcn_rcpf(1.f + __expf(-1.5957691f*u));
        int row = mf*16 + lg*4 + r;
        int col = wid*16 + l15;
        *(u16*)(hb + row*256 + ((col*2) ^ ((row&15)<<4))) = f2b(v);
      }
    asm volatile("s_waitcnt lgkmcnt(0)" ::: "memory");
    __builtin_amdgcn_s_barrier();
    __builtin_amdgcn_sched_barrier(0);

    // ---- GEMM2: 12 barrier-free steps (ks 0..3 x t 0..2) ----
    #pragma unroll
    for (int ks = 0; ks < 4; ++ks){
      int k0 = ks*32 + lg*8;
      bf16x8 pa[2];
      #pragma unroll
      for (int mf = 0; mf < 2; ++mf){
        int row = mf*16 + l15;
        pa[mf] = *(const bf16x8*)(hb + row*256 + ((k0*2) ^ ((row&15)<<4)));
      }
      #pragma unroll
      for (int t = 0; t < 3; ++t){
        int st = ks*3 + t;
        asm volatile("s_waitcnt vmcnt(4)" ::: "memory");
        __builtin_amdgcn_sched_barrier(0);
        {
          int rp = st + 17;
          char* dst = Wb + ((st+5)%6)*8192 + wid*1024;
          if (rp < 24)       gld16(dst, w2c + (size_t)(rp-12)*8192 + goff);
          else if (hci < 11) gld16(dst, w1n + (size_t)(rp-24)*8192 + goff);
          else               gld16(dst, (const char*)w1s + goff);   // dummy: rhythm keeper
        }
        char* Wcur = Wb + (st%6)*8192;
        bf16x8 wv = *(const bf16x8*)(Wcur + rowl*64 + wswz);
        #pragma unroll
        for (int mf = 0; mf < 2; ++mf)
          acc2[mf][t] = __builtin_amdgcn_mfma_f32_16x16x32_bf16(pa[mf], wv, acc2[mf][t], 0, 0, 0);
      }
    }
    asm volatile("s_waitcnt lgkmcnt(0)" ::: "memory");
    __builtin_amdgcn_s_barrier();
    __builtin_amdgcn_sched_barrier(0);
  }
  __syncthreads();                          // drain all (incl. dummies) before hb alias

  // ---- LN2 (cross-wave via LDS) + residual epilogue (32 rows) ----
  float* part = (float*)hb;                 // [32][8][2] f32
  float* lnf  = (float*)(hb + 2048);        // [32][2]
  float s1a[2][4], s2a[2][4];
  #pragma unroll
  for (int mf = 0; mf < 2; ++mf)
    #pragma unroll
    for (int r = 0; r < 4; ++r){
      float p1 = acc2[mf][0][r] + acc2[mf][1][r] + acc2[mf][2][r];
      float p2 = acc2[mf][0][r]*acc2[mf][0][r] + acc2[mf][1][r]*acc2[mf][1][r]
               + acc2[mf][2][r]*acc2[mf][2][r];
      #pragma unroll
      for (int off = 1; off < 16; off <<= 1){
        p1 += __shfl_xor(p1, off, 64);
        p2 += __shfl_xor(p2, off, 64);
      }
      s1a[mf][r] = p1; s2a[mf][r] = p2;
    }
  if (l15 == 0){
    #pragma unroll
    for (int mf = 0; mf < 2; ++mf)
      #pragma unroll
      for (int r = 0; r < 4; ++r){
        int row = mf*16 + lg*4 + r;
        part[(row*8 + wid)*2]     = s1a[mf][r];
        part[(row*8 + wid)*2 + 1] = s2a[mf][r];
      }
  }
  __syncthreads();
  if (tid < 32){
    float t1 = 0.f, t2 = 0.f;
    #pragma unroll
    for (int w = 0; w < 8; ++w){
      t1 += part[(tid*8 + w)*2];
      t2 += part[(tid*8 + w)*2 + 1];
    }
    float mu = t1*(1.f/384.f);
    lnf[tid*2]     = mu;
    lnf[tid*2 + 1] = rsqrtf(t2*(1.f/384.f) - mu*mu + 1e-5f);
  }
  __syncthreads();
  #pragma unroll
  for (int mf = 0; mf < 2; ++mf)
    #pragma unroll
    for (int r = 0; r < 4; ++r){
      int row = mf*16 + lg*4 + r;
      float mu = lnf[row*2], rstd = lnf[row*2 + 1];
      #pragma unroll
      for (int t = 0; t < 3; ++t){
        int col = (wid + 8*t)*16 + l15;
        float resid = x1[(size_t)(gt0 + row)*DIM + col];
        out[(size_t)(gt0 + row)*DIM + col] =
            resid + (acc2[mf][t][r]-mu)*rstd*n2g[col] + n2b[col];
      }
    }
}

extern "C" void kernel_launch(void* const* d_in, const int* in_sizes, int n_in,
                              void* d_out, int out_size, void* d_ws, size_t ws_size,
                              hipStream_t stream){
  const float* x           = (const float*)d_in[0];
  const float* qkv_w       = (const float*)d_in[1];
  const float* q_bias      = (const float*)d_in[2];
  const float* v_bias      = (const float*)d_in[3];
  const float* logit_scale = (const float*)d_in[4];
  const float* cpb_w1      = (const float*)d_in[5];
  const float* cpb_b1      = (const float*)d_in[6];
  const float* cpb_w2      = (const float*)d_in[7];
  const float* proj_w      = (const float*)d_in[8];
  const float* proj_b      = (const float*)d_in[9];
  const float* n1g         = (const float*)d_in[10];
  const float* n1b         = (const float*)d_in[11];
  const float* n2g         = (const float*)d_in[12];
  const float* n2b         = (const float*)d_in[13];
  const float* mlp_w1      = (const float*)d_in[14];
  const float* mlp_b1      = (const float*)d_in[15];
  const float* mlp_w2      = (const float*)d_in[16];
  const float* mlp_b2      = (const float*)d_in[17];

  char* ws = (char*)d_ws;
  float* tab      = (float*)ws;
  float* biasfull = (float*)(ws + 8192);
  u16*  Qg     = (u16*)(ws + 126976);                  // aliased by outwin after k_attn2
  u16*  qkvbf  = (u16*)(ws + 126976 + 77070336ull);
  u16*  pws    = (u16*)(ws + 126976 + 77070336ull + 884736ull);
  u16*  w1s    = (u16*)(ws + 126976 + 77070336ull + 884736ull + 294912ull);
  u16*  w2s    = (u16*)(ws + 126976 + 77070336ull + 884736ull + 294912ull + 1179648ull);
  u16*  Kg     = (u16*)d_out;
  u16*  Vg     = Kg + (size_t)NWIN*18816;
  u16*  outwin = Qg;
  float* x1  = (float*)d_out;
  float* out = (float*)d_out;

  hipLaunchKernelGGL(k_bias, dim3(169), dim3(256), 0, stream, cpb_w1, cpb_b1, cpb_w2, tab);
  hipLaunchKernelGGL(k_bias2, dim3(12), dim3(256), 0, stream, tab, biasfull);
  hipLaunchKernelGGL(k_wconv, dim3(1024), dim3(256), 0, stream,
                     mlp_w1, mlp_w2, qkv_w, proj_w, w1s, w2s, qkvbf, pws);
  hipLaunchKernelGGL(k_qkv, dim3(NWIN, 3), dim3(512), 0, stream,
                     x, qkvbf, q_bias, v_bias, logit_scale, Qg, Kg, Vg);
  hipLaunchKernelGGL(k_attn2, dim3(NWIN), dim3(256), 0, stream,
                     Qg, Kg, Vg, biasfull, outwin);
  // dynamic LDS: 24K sb + 48K ring = 73728 B -> 2 blocks/CU
  hipLaunchKernelGGL(k_proj, dim3(TOKENS/32), dim3(512), 73728, stream,
                     outwin, pws, proj_b, x, n1g, n1b, x1);
  // dynamic LDS: 24K xb + 48K ring + 8K hb = 81920 B -> 2 blocks/CU
  hipLaunchKernelGGL(k_mlp, dim3(TOKENS/32), dim3(512), 81920, stream,
                     x1, w1s, mlp_b1, w2s, mlp_b2, n2g, n2b, out);
}

// Round 27
// 956.000 us; speedup vs baseline: 1.0228x; 1.0214x over previous
//
#include <hip/hip_runtime.h>
#include <hip/hip_bf16.h>
#include <math.h>

#define DIM 384
#define NH 12
#define HD 32
#define NWIN 2048          // B * 64 windows
#define TOKENS 100352      // B * 56 * 56
#define NSTG 6             // W-tile ring depth

typedef unsigned short u16;
typedef unsigned int u32;
typedef __attribute__((ext_vector_type(8))) short bf16x8;
typedef __attribute__((ext_vector_type(4))) float f32x4;

__device__ __forceinline__ float b2f(u16 u){ return __uint_as_float(((u32)u) << 16); }
__device__ __forceinline__ u16 f2b(float f){
  u32 x = __float_as_uint(f);
  return (u16)((x + 0x7FFFu + ((x >> 16) & 1u)) >> 16);   // RNE
}

// async global->LDS, 16B per lane; LDS dest = wave-uniform base + lane*16
__device__ __forceinline__ void gld16(void* lds, const void* g){
  __builtin_amdgcn_global_load_lds((const __attribute__((address_space(1))) u32*)g,
                                   (__attribute__((address_space(3))) u32*)lds, 16, 0, 0);
}

// ---------------- weight pre-convert fp32 -> bf16 ----------------
// w1s/w2s/pws: staging-tile layout. Tile = 8KB = [128 rows][4 granules][8 elems],
// granule pre-swizzled with selector s(r) = (r>>1)&3 (bank-spread verified:
// conflicts 3.05e7 -> 1.56e6). qwbf: plain [row][k] bf16.
__global__ void k_wconv(const float* __restrict__ w1, const float* __restrict__ w2,
                        const float* __restrict__ qw, const float* __restrict__ pw,
                        u16* __restrict__ w1s, u16* __restrict__ w2s,
                        u16* __restrict__ qwbf, u16* __restrict__ pws){
  const int n12 = 1536*384, n3 = 1152*384, n4 = 384*384;
  for (int d = blockIdx.x*blockDim.x + threadIdx.x; d < n12; d += gridDim.x*blockDim.x){
    int tile = d >> 12, w = d & 4095;
    int rowl = w >> 5, g = (w >> 3) & 3, e = w & 7;
    int hci = tile / 12, rem = tile - hci*12;
    int kk = ((g ^ ((rowl >> 1) & 3)) << 3) + e;
    w1s[d] = f2b(w1[(size_t)(hci*128 + rowl)*384 + rem*32 + kk]);
    int ks = rem / 3, t = rem - ks*3;
    w2s[d] = f2b(w2[(size_t)(t*128 + rowl)*1536 + hci*128 + ks*32 + kk]);
    if (d < n3) qwbf[d] = f2b(qw[d]);
    if (d < n4){
      int pt = d >> 12, pwd = d & 4095;
      int prl = pwd >> 5, pg = (pwd >> 3) & 3, pe = pwd & 7;
      int pks = pt / 3, ptt = pt - pks*3;
      int pkk = ((pg ^ ((prl >> 1) & 3)) << 3) + pe;
      pws[d] = f2b(pw[(size_t)(ptt*128 + prl)*384 + pks*32 + pkk]);
    }
  }
}

// ---------------- CPB bias table: tab[169][12] ----------------
__global__ void k_bias(const float* __restrict__ w1, const float* __restrict__ b1,
                       const float* __restrict__ w2, float* __restrict__ tab){
  __shared__ float hid[512];
  int e = blockIdx.x;
  int i = e / 13, j = e % 13;
  float t0 = (float)(i - 6) * (8.0f / 6.0f);
  float t1 = (float)(j - 6) * (8.0f / 6.0f);
  t0 = copysignf(log2f(fabsf(t0) + 1.f) * (1.f / 3.f), t0);
  t1 = copysignf(log2f(fabsf(t1) + 1.f) * (1.f / 3.f), t1);
  for (int jj = threadIdx.x; jj < 512; jj += blockDim.x)
    hid[jj] = fmaxf(w1[jj*2]*t0 + w1[jj*2+1]*t1 + b1[jj], 0.f);
  __syncthreads();
  if (threadIdx.x < 12){
    float s = 0.f;
    for (int jj = 0; jj < 512; ++jj) s += hid[jj] * w2[threadIdx.x*512 + jj];
    tab[e*12 + threadIdx.x] = s;
  }
}

// ---------------- expand: biasfull[h][i*49+j] = 16*sigmoid(tab[rpi(i,j)][h]) ----------------
__global__ void k_bias2(const float* __restrict__ tab, float* __restrict__ biasfull){
  int h = blockIdx.x;
  for (int e = threadIdx.x; e < 49*49; e += blockDim.x){
    int i = e / 49, j = e - (e/49)*49;
    int ih = i/7, iw = i - ih*7, jh = j/7, jw = j - jh*7;
    float bv = tab[((ih-jh+6)*13 + (iw-jw+6))*12 + h];
    biasfull[h*2401 + e] = 16.f / (1.f + expf(-bv));
  }
}

// ---------------- k_qkv: windowed QKV GEMM, LDS double-buffered ----------------
__device__ __forceinline__ void qkv_stage(
    int kc, char* Ad, char* Bd, const float* __restrict__ x, size_t asrc,
    bool arok, int ar, int aq, const u16* __restrict__ bbase, int tid){
  if (arok){
    float4 v4 = *(const float4*)(x + asrc + kc + aq*4);
    u16 p0=f2b(v4.x), p1=f2b(v4.y), p2=f2b(v4.z), p3=f2b(v4.w);
    *(uint2*)(Ad + ar*80 + aq*8) = (uint2){(u32)p0|((u32)p1<<16), (u32)p2|((u32)p3<<16)};
  } else {
    *(uint2*)(Ad + ar*80 + aq*8) = (uint2){0u, 0u};
  }
  #pragma unroll
  for (int i = 0; i < 3; ++i){
    int s = tid + i*512, n = s >> 2, g = s & 3;
    bf16x8 v = *(const bf16x8*)(bbase + (size_t)n*DIM + kc + (g ^ (n&3))*8);
    *(bf16x8*)(Bd + n*64 + g*16) = v;
  }
}

__global__ __launch_bounds__(512, 4) void k_qkv(
    const float* __restrict__ x, const u16* __restrict__ qkvbf,
    const float* __restrict__ q_bias, const float* __restrict__ v_bias,
    const float* __restrict__ logit_scale,
    u16* __restrict__ Qg, u16* __restrict__ Kg, u16* __restrict__ Vg){
  __shared__ __align__(16) char Ab[2][5120];    // [64][80B] bf16
  __shared__ __align__(16) char Bb[2][24576];   // [384][64B] bf16, granule-swz

  int tid = threadIdx.x;
  int lane = tid & 63, wid = tid >> 6;
  int l15 = lane & 15, lg = lane >> 4;
  int wm = wid >> 2, wn = wid & 3;
  int win = blockIdx.x, NT = blockIdx.y;
  int b = win >> 6, wi = win & 63, wh = wi >> 3, ww = wi & 7;

  int ar = tid >> 3, aq = tid & 7;
  bool arok = ar < 49;
  size_t asrc = 0;
  if (arok){
    int th = ar / 7, tw = ar - (ar/7)*7;
    int gh = wh*7 + th + 3; if (gh >= 56) gh -= 56;
    int gw = ww*7 + tw + 3; if (gw >= 56) gw -= 56;
    asrc = ((size_t)(b*3136 + gh*56 + gw))*DIM;
  }
  const u16* bbase = qkvbf + (size_t)NT*384*DIM;

  f32x4 acc[2][6];
  #pragma unroll
  for (int mf = 0; mf < 2; ++mf)
    #pragma unroll
    for (int nf = 0; nf < 6; ++nf) acc[mf][nf] = (f32x4){0.f,0.f,0.f,0.f};

  qkv_stage(0, Ab[0], Bb[0], x, asrc, arok, ar, aq, bbase, tid);
  __syncthreads();

  for (int t = 0; t < 12; ++t){
    int cur = t & 1;
    if (t < 11)
      qkv_stage((t+1)*32, Ab[cur^1], Bb[cur^1], x, asrc, arok, ar, aq, bbase, tid);
    bf16x8 af[2];
    #pragma unroll
    for (int mf = 0; mf < 2; ++mf){
      int row = wm*32 + mf*16 + l15;
      af[mf] = *(const bf16x8*)(Ab[cur] + row*80 + lg*16);
    }
    #pragma unroll
    for (int nf = 0; nf < 6; ++nf){
      int n = wn*96 + nf*16 + l15;
      bf16x8 bfv = *(const bf16x8*)(Bb[cur] + n*64 + ((lg ^ (n&3))*16));
      #pragma unroll
      for (int mf = 0; mf < 2; ++mf)
        acc[mf][nf] = __builtin_amdgcn_mfma_f32_16x16x32_bf16(af[mf], bfv, acc[mf][nf], 0, 0, 0);
    }
    __syncthreads();
  }

  if (NT == 0){        // Q: +bias, cosine norm, * scale
    #pragma unroll
    for (int p = 0; p < 3; ++p){
      int h = wn*3 + p;
      float qb0 = q_bias[h*32 + l15], qb1 = q_bias[h*32 + 16 + l15];
      float sc = __expf(fminf(logit_scale[h], 4.6051702f));
      #pragma unroll
      for (int mf = 0; mf < 2; ++mf)
        #pragma unroll
        for (int r = 0; r < 4; ++r){
          float a0 = acc[mf][2*p][r] + qb0;
          float a1 = acc[mf][2*p+1][r] + qb1;
          float sq = a0*a0 + a1*a1;
          #pragma unroll
          for (int off = 1; off < 16; off <<= 1) sq += __shfl_xor(sq, off, 64);
          float rq = sc / fmaxf(sqrtf(sq), 1e-12f);
          int grow = wm*32 + mf*16 + lg*4 + r;
          if (grow < 49){
            u16* dst = Qg + (size_t)win*18816 + h*1568 + grow*32;
            dst[l15]      = f2b(a0*rq);
            dst[16 + l15] = f2b(a1*rq);
          }
        }
    }
  } else if (NT == 1){ // K: cosine norm only
    #pragma unroll
    for (int p = 0; p < 3; ++p){
      int h = wn*3 + p;
      #pragma unroll
      for (int mf = 0; mf < 2; ++mf)
        #pragma unroll
        for (int r = 0; r < 4; ++r){
          float a0 = acc[mf][2*p][r], a1 = acc[mf][2*p+1][r];
          float sk = a0*a0 + a1*a1;
          #pragma unroll
          for (int off = 1; off < 16; off <<= 1) sk += __shfl_xor(sk, off, 64);
          float rk = 1.f / fmaxf(sqrtf(sk), 1e-12f);
          int grow = wm*32 + mf*16 + lg*4 + r;
          if (grow < 49){
            u16* dst = Kg + (size_t)win*18816 + h*1568 + grow*32;
            dst[l15]      = f2b(a0*rk);
            dst[16 + l15] = f2b(a1*rk);
          }
        }
    }
  } else {             // V: +bias
    #pragma unroll
    for (int nf = 0; nf < 6; ++nf){
      int col = wn*96 + nf*16 + l15;
      int h = col >> 5, c = col & 31;
      float vb = v_bias[col];
      #pragma unroll
      for (int mf = 0; mf < 2; ++mf){
        int gbase = wm*32 + mf*16 + lg*4;
        u16* dst = Vg + (size_t)win*18816 + h*1568 + c;
        #pragma unroll
        for (int r = 0; r < 4; ++r){
          int grow = gbase + r;
          if (grow < 49) dst[grow*32] = f2b(acc[mf][nf][r] + vb);
        }
      }
    }
  }
}

// ---------------- k_attn2: per-window attention (Q/K/V precomputed) ----------------
__global__ __launch_bounds__(256, 3) void k_attn2(
    const u16* __restrict__ Qg, const u16* __restrict__ Kg, const u16* __restrict__ Vg,
    const float* __restrict__ biasfull, u16* __restrict__ outwin){
  __shared__ __align__(16) char pb[4][2304];    // per-wave P [16][144B]

  int tid = threadIdx.x, lane = tid & 63, wid = tid >> 6;
  int l15 = lane & 15, lg = lane >> 4;
  int win = blockIdx.x;
  int wi = win & 63, wh = wi >> 3, ww = wi & 7;

  float mask16[4][4];
  int   bidx[4][4];
  #pragma unroll
  for (int nf = 0; nf < 4; ++nf){
    int j = nf*16 + l15;
    int j2 = j < 49 ? j : 48;
    int jh = j2/7, jw = j2 - jh*7;
    int ghj = wh*7+jh, gwj = ww*7+jw;
    int zj = (ghj<49?0:(ghj<53?1:2))*3 + (gwj<49?0:(gwj<53?1:2));
    #pragma unroll
    for (int r = 0; r < 4; ++r){
      int i = wid*16 + lg*4 + r;
      int i2 = i < 49 ? i : 48;
      int ih = i2/7, iw = i2 - ih*7;
      int ghi = wh*7+ih, gwi = ww*7+iw;
      int zi = (ghi<49?0:(ghi<53?1:2))*3 + (gwi<49?0:(gwi<53?1:2));
      mask16[nf][r] = (j < 49) ? (zi != zj ? -100.f : 0.f) : -1e30f;
      bidx[nf][r]   = i2*49 + j2;
    }
  }

  const u16* qwin = Qg + (size_t)win*18816;
  const u16* kwin = Kg + (size_t)win*18816;
  const u16* vwin = Vg + (size_t)win*18816;
  char* pbw = pb[wid];

  int arow = wid*16 + l15;
  int arc  = arow < 49 ? arow : 48;

  bf16x8 qa[12];
  #pragma unroll
  for (int h = 0; h < 12; ++h)
    qa[h] = *(const bf16x8*)(qwin + h*1568 + arc*32 + lg*8);
  __syncthreads();                              // all Q reads done before outwin writes

  #pragma unroll
  for (int h = 0; h < 12; ++h){
    bf16x8 kb[4];
    #pragma unroll
    for (int nf = 0; nf < 4; ++nf){
      int j = nf*16 + l15; int j2 = j < 49 ? j : 48;
      kb[nf] = *(const bf16x8*)(kwin + h*1568 + j2*32 + lg*8);
    }
    bf16x8 vb0[2], vb1[2];
    #pragma unroll
    for (int ksp = 0; ksp < 2; ++ksp){
      #pragma unroll
      for (int tt = 0; tt < 8; ++tt){
        int j = ksp*32 + lg*8 + tt; int j2 = j < 49 ? j : 48;
        vb0[ksp][tt] = (short)vwin[h*1568 + j2*32 + l15];
        vb1[ksp][tt] = (short)vwin[h*1568 + j2*32 + 16 + l15];
      }
    }
    float bias16[4][4];
    #pragma unroll
    for (int nf = 0; nf < 4; ++nf)
      #pragma unroll
      for (int r = 0; r < 4; ++r)
        bias16[nf][r] = biasfull[h*2401 + bidx[nf][r]];
    f32x4 s[4];
    #pragma unroll
    for (int nf = 0; nf < 4; ++nf)
      s[nf] = __builtin_amdgcn_mfma_f32_16x16x32_bf16(qa[h], kb[nf],
                (f32x4){0.f,0.f,0.f,0.f}, 0, 0, 0);
    #pragma unroll
    for (int nf = 0; nf < 4; ++nf)
      #pragma unroll
      for (int r = 0; r < 4; ++r)
        s[nf][r] += bias16[nf][r] + mask16[nf][r];
    #pragma unroll
    for (int r = 0; r < 4; ++r){
      float m = fmaxf(fmaxf(s[0][r], s[1][r]), fmaxf(s[2][r], s[3][r]));
      #pragma unroll
      for (int off = 1; off < 16; off <<= 1) m = fmaxf(m, __shfl_xor(m, off, 64));
      float e0 = __expf(s[0][r]-m), e1 = __expf(s[1][r]-m);
      float e2 = __expf(s[2][r]-m), e3 = __expf(s[3][r]-m);
      float sum = e0+e1+e2+e3;
      #pragma unroll
      for (int off = 1; off < 16; off <<= 1) sum += __shfl_xor(sum, off, 64);
      float rs = 1.f/sum;
      s[0][r] = e0*rs; s[1][r] = e1*rs; s[2][r] = e2*rs; s[3][r] = e3*rs;
    }
    #pragma unroll
    for (int nf = 0; nf < 4; ++nf){
      int j = nf*16 + l15;
      #pragma unroll
      for (int r = 0; r < 4; ++r)
        *(u16*)(pbw + (lg*4+r)*144 + j*2) = f2b(s[nf][r]);
    }
    f32x4 o0 = (f32x4){0.f,0.f,0.f,0.f}, o1 = o0;
    #pragma unroll
    for (int ksp = 0; ksp < 2; ++ksp){
      bf16x8 pa = *(const bf16x8*)(pbw + l15*144 + ksp*64 + lg*16);
      o0 = __builtin_amdgcn_mfma_f32_16x16x32_bf16(pa, vb0[ksp], o0, 0, 0, 0);
      o1 = __builtin_amdgcn_mfma_f32_16x16x32_bf16(pa, vb1[ksp], o1, 0, 0, 0);
    }
    #pragma unroll
    for (int r = 0; r < 4; ++r){
      int row = wid*16 + lg*4 + r;
      if (row < 49){
        u16* dst = outwin + ((size_t)win*49 + row)*DIM + h*HD;
        dst[l15]      = f2b(o0[r]);
        dst[16 + l15] = f2b(o1[r]);
      }
    }
  }
}

// ---------------- k_pm: fused proj+LN1+MLP+LN2 (splice of k_proj v3 & k_mlp v9c) ----------------
// Same 32-token/block geometry, same wave-private ring + vmcnt(4) rhythm. x1 never
// touches HBM: proj tail's 5 dummy slots fetch w1s tiles 0..4 (= MLP prologue,
// slot i == tile i); post-GEMM __syncthreads (vmcnt-0 drain) re-establishes the
// v9c entry state; LN1 part/lnf relocated Wb->hb (ring live); x1 values written
// bf16 to sb-as-xb (element swz (col*2)^((row&15)<<4), consistent with granule
// form: swz bits 4-7 disjoint from e*2 bits 1-3) and kept fp32 in resid regs for
// the final epilogue (same per-thread (row,col) ownership in both phases).
__global__ __launch_bounds__(512, 4) void k_pm(
    const u16* __restrict__ outwin, const u16* __restrict__ pws,
    const float* __restrict__ proj_b, const float* __restrict__ x,
    const float* __restrict__ n1g, const float* __restrict__ n1b,
    const u16* __restrict__ w1s, const float* __restrict__ b1,
    const u16* __restrict__ w2s, const float* __restrict__ b2,
    const float* __restrict__ n2g, const float* __restrict__ n2b,
    float* __restrict__ out){
  extern __shared__ char smem[];
  char* sb = smem;                          // [32][768B] bf16: proj-in, then xb
  char* Wb = smem + 24576;                  // NSTG x 8KB ring (wave-private 1KB slices)
  char* hb = smem + 24576 + 49152;          // 8KB: LN1 part/lnf, then GELU hb, then LN2

  int tid  = threadIdx.x;
  int lane = tid & 63, wid = tid >> 6;
  int l15  = lane & 15, lg = lane >> 4;
  int gt0 = blockIdx.x * 32;

  // ---- stage proj input (window-reverse + un-shift gather) ----
  for (int e = tid; e < 32*48; e += 512){
    int r = e / 48, q8 = e - (e/48)*48;
    int gtok = gt0 + r;
    int b = gtok / 3136, r2 = gtok - b*3136;
    int oh = r2 / 56, ow = r2 - oh*56;
    int hs = oh + 53; if (hs >= 56) hs -= 56;
    int ws2 = ow + 53; if (ws2 >= 56) ws2 -= 56;
    int win = b*64 + (hs/7)*8 + (ws2/7);
    int row = (hs%7)*7 + (ws2%7);
    bf16x8 v = *(const bf16x8*)(outwin + ((size_t)win*49 + row)*DIM + q8*8);
    *(bf16x8*)(sb + r*768 + ((q8*16) ^ ((r&15)<<4))) = v;
  }

  f32x4 acc[2][3];
  #pragma unroll
  for (int mf = 0; mf < 2; ++mf)
    #pragma unroll
    for (int t = 0; t < 3; ++t){
      float pbv = proj_b[(wid + 8*t)*16 + l15];
      acc[mf][t] = (f32x4){pbv, pbv, pbv, pbv};
    }

  int goff = tid*16;
  int rowl = wid*16 + l15;
  int wswz = (lg ^ ((rowl >> 1) & 3)) << 4;
  #pragma unroll
  for (int sp = 0; sp < NSTG-1; ++sp)
    gld16(Wb + sp*8192 + wid*1024, (const char*)pws + (size_t)sp*8192 + goff);
  __syncthreads();

  // ---- proj GEMM: 36 counted-vmcnt steps; tail (st>=31) issues w1s tiles 0..4 ----
  #pragma unroll
  for (int ks = 0; ks < 12; ++ks){
    int k0 = ks*32 + lg*8;
    bf16x8 pa[2];
    #pragma unroll
    for (int mf = 0; mf < 2; ++mf){
      int row = mf*16 + l15;
      pa[mf] = *(const bf16x8*)(sb + row*768 + ((k0*2) ^ ((row&15)<<4)));
    }
    #pragma unroll
    for (int t = 0; t < 3; ++t){
      int st = ks*3 + t;
      asm volatile("s_waitcnt vmcnt(4)" ::: "memory");
      __builtin_amdgcn_sched_barrier(0);
      {
        int rp = st + 5;
        char* dst = Wb + ((st+5)%6)*8192 + wid*1024;
        if (rp < 36) gld16(dst, (const char*)pws + (size_t)rp*8192 + goff);
        else         gld16(dst, (const char*)w1s + (size_t)(rp-36)*8192 + goff); // MLP prologue
      }
      char* Wcur = Wb + (st%6)*8192;
      bf16x8 wv = *(const bf16x8*)(Wcur + rowl*64 + wswz);
      #pragma unroll
      for (int mf = 0; mf < 2; ++mf)
        acc[mf][t] = __builtin_amdgcn_mfma_f32_16x16x32_bf16(pa[mf], wv, acc[mf][t], 0, 0, 0);
    }
  }
  __syncthreads();   // vmcnt(0) drained: w1s tiles 0..4 resident in slots 0..4

  // ---- LN1 (cross-wave via hb; ring is live with w1s prologue) ----
  {
    float* part = (float*)hb;              // [32][8][2] f32
    float* lnf  = (float*)(hb + 2048);     // [32][2]
    float s1a[2][4], s2a[2][4];
    #pragma unroll
    for (int mf = 0; mf < 2; ++mf)
      #pragma unroll
      for (int r = 0; r < 4; ++r){
        float p1 = acc[mf][0][r] + acc[mf][1][r] + acc[mf][2][r];
        float p2 = acc[mf][0][r]*acc[mf][0][r] + acc[mf][1][r]*acc[mf][1][r]
                 + acc[mf][2][r]*acc[mf][2][r];
        #pragma unroll
        for (int off = 1; off < 16; off <<= 1){
          p1 += __shfl_xor(p1, off, 64);
          p2 += __shfl_xor(p2, off, 64);
        }
        s1a[mf][r] = p1; s2a[mf][r] = p2;
      }
    if (l15 == 0){
      #pragma unroll
      for (int mf = 0; mf < 2; ++mf)
        #pragma unroll
        for (int r = 0; r < 4; ++r){
          int row = mf*16 + lg*4 + r;
          part[(row*8 + wid)*2]     = s1a[mf][r];
          part[(row*8 + wid)*2 + 1] = s2a[mf][r];
        }
    }
    __syncthreads();
    if (tid < 32){
      float t1 = 0.f, t2 = 0.f;
      #pragma unroll
      for (int w = 0; w < 8; ++w){
        t1 += part[(tid*8 + w)*2];
        t2 += part[(tid*8 + w)*2 + 1];
      }
      float mu = t1*(1.f/384.f);
      lnf[tid*2]     = mu;
      lnf[tid*2 + 1] = rsqrtf(t2*(1.f/384.f) - mu*mu + 1e-5f);
    }
    __syncthreads();

    // ---- x1 = LN1(proj)+resid: bf16 -> sb(xb layout), fp32 kept in registers ----
    float residv[2][3][4];
    #pragma unroll
    for (int mf = 0; mf < 2; ++mf)
      #pragma unroll
      for (int r = 0; r < 4; ++r){
        int row = mf*16 + lg*4 + r;
        float mu = lnf[row*2], rstd = lnf[row*2 + 1];
        #pragma unroll
        for (int t = 0; t < 3; ++t){
          int col = (wid + 8*t)*16 + l15;
          float xv = (acc[mf][t][r]-mu)*rstd*n1g[col] + n1b[col]
                   + x[(size_t)(gt0 + row)*DIM + col];
          residv[mf][t][r] = xv;
          *(u16*)(sb + row*768 + ((col*2) ^ ((row&15)<<4))) = f2b(xv);
        }
      }
    __syncthreads();   // xb complete; lnf reads done -> hb free for GELU

    // ---- MLP phase (k_mlp v9c body, sb as xb, prologue pre-staged) ----
    int b1c = wid*16 + l15;
    float b1r0 = b1[b1c],          b1r1 = b1[128 + b1c],  b1r2 = b1[256 + b1c];
    float b1r3 = b1[384 + b1c],    b1r4 = b1[512 + b1c],  b1r5 = b1[640 + b1c];
    float b1r6 = b1[768 + b1c],    b1r7 = b1[896 + b1c],  b1r8 = b1[1024 + b1c];
    float b1r9 = b1[1152 + b1c],   b1r10 = b1[1280 + b1c], b1r11 = b1[1408 + b1c];

    f32x4 acc2[2][3];
    #pragma unroll
    for (int mf = 0; mf < 2; ++mf)
      #pragma unroll
      for (int t = 0; t < 3; ++t){
        float bb = b2[(wid + 8*t)*16 + l15];
        acc2[mf][t] = (f32x4){bb, bb, bb, bb};
      }

    for (int hci = 0; hci < 12; ++hci){
      const char* w1c = (const char*)w1s + (size_t)hci*98304;
      const char* w2c = (const char*)w2s + (size_t)hci*98304;
      const char* w1n = (const char*)w1s + (size_t)(hci+1)*98304;

      float bb = hci==0?b1r0 : hci==1?b1r1 : hci==2?b1r2 : hci==3?b1r3 :
                 hci==4?b1r4 : hci==5?b1r5 : hci==6?b1r6 : hci==7?b1r7 :
                 hci==8?b1r8 : hci==9?b1r9 : hci==10?b1r10 : b1r11;
      f32x4 accH[2];
      #pragma unroll
      for (int mf = 0; mf < 2; ++mf) accH[mf] = (f32x4){bb, bb, bb, bb};

      // ---- GEMM1: 12 barrier-free counted-vmcnt steps ----
      #pragma unroll
      for (int ksp = 0; ksp < 12; ++ksp){
        asm volatile("s_waitcnt vmcnt(4)" ::: "memory");
        __builtin_amdgcn_sched_barrier(0);
        {
          int rp = ksp + 5;
          char* dst = Wb + ((ksp+5)%6)*8192 + wid*1024;
          const char* src = (rp < 12) ? (w1c + (size_t)rp*8192)
                                      : (w2c + (size_t)(rp-12)*8192);
          gld16(dst, src + goff);
        }
        char* Wcur = Wb + (ksp%6)*8192;
        int k0 = ksp*32 + lg*8;
        bf16x8 wfr = *(const bf16x8*)(Wcur + rowl*64 + wswz);
        bf16x8 afr[2];
        #pragma unroll
        for (int mf = 0; mf < 2; ++mf){
          int row = mf*16 + l15;
          afr[mf] = *(const bf16x8*)(sb + row*768 + ((k0*2) ^ ((row&15)<<4)));
        }
        #pragma unroll
        for (int mf = 0; mf < 2; ++mf)
          accH[mf] = __builtin_amdgcn_mfma_f32_16x16x32_bf16(afr[mf], wfr, accH[mf], 0, 0, 0);
      }

      // ---- tanh-form GELU -> hb ----
      #pragma unroll
      for (int mf = 0; mf < 2; ++mf)
        #pragma unroll
        for (int r = 0; r < 4; ++r){
          float v = accH[mf][r];
          float u = v*(1.f + 0.044715f*v*v);
          v = v * __builtin_amdgcn_rcpf(1.f + __expf(-1.5957691f*u));
          int row = mf*16 + lg*4 + r;
          int col = wid*16 + l15;
          *(u16*)(hb + row*256 + ((col*2) ^ ((row&15)<<4))) = f2b(v);
        }
      asm volatile("s_waitcnt lgkmcnt(0)" ::: "memory");
      __builtin_amdgcn_s_barrier();
      __builtin_amdgcn_sched_barrier(0);

      // ---- GEMM2: 12 barrier-free steps (ks 0..3 x t 0..2) ----
      #pragma unroll
      for (int ks = 0; ks < 4; ++ks){
        int k0 = ks*32 + lg*8;
        bf16x8 pa2[2];
        #pragma unroll
        for (int mf = 0; mf < 2; ++mf){
          int row = mf*16 + l15;
          pa2[mf] = *(const bf16x8*)(hb + row*256 + ((k0*2) ^ ((row&15)<<4)));
        }
        #pragma unroll
        for (int t = 0; t < 3; ++t){
          int st = ks*3 + t;
          asm volatile("s_waitcnt vmcnt(4)" ::: "memory");
          __builtin_amdgcn_sched_barrier(0);
          {
            int rp = st + 17;
            char* dst = Wb + ((st+5)%6)*8192 + wid*1024;
            if (rp < 24)       gld16(dst, w2c + (size_t)(rp-12)*8192 + goff);
            else if (hci < 11) gld16(dst, w1n + (size_t)(rp-24)*8192 + goff);
            else               gld16(dst, (const char*)w1s + goff);   // dummy: rhythm keeper
          }
          char* Wcur = Wb + (st%6)*8192;
          bf16x8 wv = *(const bf16x8*)(Wcur + rowl*64 + wswz);
          #pragma unroll
          for (int mf = 0; mf < 2; ++mf)
            acc2[mf][t] = __builtin_amdgcn_mfma_f32_16x16x32_bf16(pa2[mf], wv, acc2[mf][t], 0, 0, 0);
        }
      }
      asm volatile("s_waitcnt lgkmcnt(0)" ::: "memory");
      __builtin_amdgcn_s_barrier();
      __builtin_amdgcn_sched_barrier(0);
    }
    __syncthreads();                        // drain all (incl. dummies) before hb alias

    // ---- LN2 (cross-wave via hb) + residual epilogue (resid from registers) ----
    float* part2 = (float*)hb;              // [32][8][2] f32
    float* lnf2  = (float*)(hb + 2048);     // [32][2]
    float t1a[2][4], t2a[2][4];
    #pragma unroll
    for (int mf = 0; mf < 2; ++mf)
      #pragma unroll
      for (int r = 0; r < 4; ++r){
        float p1 = acc2[mf][0][r] + acc2[mf][1][r] + acc2[mf][2][r];
        float p2 = acc2[mf][0][r]*acc2[mf][0][r] + acc2[mf][1][r]*acc2[mf][1][r]
                 + acc2[mf][2][r]*acc2[mf][2][r];
        #pragma unroll
        for (int off = 1; off < 16; off <<= 1){
          p1 += __shfl_xor(p1, off, 64);
          p2 += __shfl_xor(p2, off, 64);
        }
        t1a[mf][r] = p1; t2a[mf][r] = p2;
      }
    if (l15 == 0){
      #pragma unroll
      for (int mf = 0; mf < 2; ++mf)
        #pragma unroll
        for (int r = 0; r < 4; ++r){
          int row = mf*16 + lg*4 + r;
          part2[(row*8 + wid)*2]     = t1a[mf][r];
          part2[(row*8 + wid)*2 + 1] = t2a[mf][r];
        }
    }
    __syncthreads();
    if (tid < 32){
      float t1 = 0.f, t2 = 0.f;
      #pragma unroll
      for (int w = 0; w < 8; ++w){
        t1 += part2[(tid*8 + w)*2];
        t2 += part2[(tid*8 + w)*2 + 1];
      }
      float mu = t1*(1.f/384.f);
      lnf2[tid*2]     = mu;
      lnf2[tid*2 + 1] = rsqrtf(t2*(1.f/384.f) - mu*mu + 1e-5f);
    }
    __syncthreads();
    #pragma unroll
    for (int mf = 0; mf < 2; ++mf)
      #pragma unroll
      for (int r = 0; r < 4; ++r){
        int row = mf*16 + lg*4 + r;
        float mu = lnf2[row*2], rstd = lnf2[row*2 + 1];
        #pragma unroll
        for (int t = 0; t < 3; ++t){
          int col = (wid + 8*t)*16 + l15;
          out[(size_t)(gt0 + row)*DIM + col] =
              residv[mf][t][r] + (acc2[mf][t][r]-mu)*rstd*n2g[col] + n2b[col];
        }
      }
  }
}

extern "C" void kernel_launch(void* const* d_in, const int* in_sizes, int n_in,
                              void* d_out, int out_size, void* d_ws, size_t ws_size,
                              hipStream_t stream){
  const float* x           = (const float*)d_in[0];
  const float* qkv_w       = (const float*)d_in[1];
  const float* q_bias      = (const float*)d_in[2];
  const float* v_bias      = (const float*)d_in[3];
  const float* logit_scale = (const float*)d_in[4];
  const float* cpb_w1      = (const float*)d_in[5];
  const float* cpb_b1      = (const float*)d_in[6];
  const float* cpb_w2      = (const float*)d_in[7];
  const float* proj_w      = (const float*)d_in[8];
  const float* proj_b      = (const float*)d_in[9];
  const float* n1g         = (const float*)d_in[10];
  const float* n1b         = (const float*)d_in[11];
  const float* n2g         = (const float*)d_in[12];
  const float* n2b         = (const float*)d_in[13];
  const float* mlp_w1      = (const float*)d_in[14];
  const float* mlp_b1      = (const float*)d_in[15];
  const float* mlp_w2      = (const float*)d_in[16];
  const float* mlp_b2      = (const float*)d_in[17];

  char* ws = (char*)d_ws;
  float* tab      = (float*)ws;
  float* biasfull = (float*)(ws + 8192);
  u16*  Qg     = (u16*)(ws + 126976);                  // aliased by outwin after k_attn2
  u16*  qkvbf  = (u16*)(ws + 126976 + 77070336ull);
  u16*  pws    = (u16*)(ws + 126976 + 77070336ull + 884736ull);
  u16*  w1s    = (u16*)(ws + 126976 + 77070336ull + 884736ull + 294912ull);
  u16*  w2s    = (u16*)(ws + 126976 + 77070336ull + 884736ull + 294912ull + 1179648ull);
  u16*  Kg     = (u16*)d_out;
  u16*  Vg     = Kg + (size_t)NWIN*18816;
  u16*  outwin = Qg;
  float* out = (float*)d_out;

  hipLaunchKernelGGL(k_bias, dim3(169), dim3(256), 0, stream, cpb_w1, cpb_b1, cpb_w2, tab);
  hipLaunchKernelGGL(k_bias2, dim3(12), dim3(256), 0, stream, tab, biasfull);
  hipLaunchKernelGGL(k_wconv, dim3(1024), dim3(256), 0, stream,
                     mlp_w1, mlp_w2, qkv_w, proj_w, w1s, w2s, qkvbf, pws);
  hipLaunchKernelGGL(k_qkv, dim3(NWIN, 3), dim3(512), 0, stream,
                     x, qkvbf, q_bias, v_bias, logit_scale, Qg, Kg, Vg);
  hipLaunchKernelGGL(k_attn2, dim3(NWIN), dim3(256), 0, stream,
                     Qg, Kg, Vg, biasfull, outwin);
  // fused proj+LN1+MLP+LN2: 24K sb/xb + 48K ring + 8K hb = 81920 B -> 2 blocks/CU
  hipLaunchKernelGGL(k_pm, dim3(TOKENS/32), dim3(512), 81920, stream,
                     outwin, pws, proj_b, x, n1g, n1b,
                     w1s, mlp_b1, w2s, mlp_b2, n2g, n2b, out);
}